// Round 1
// baseline (1059.313 us; speedup 1.0000x reference)
//
#include <hip/hip_runtime.h>
#include <math.h>

#define BB 4
#define TT 2048
#define DD 1024
#define DLb 128
#define EE 8
#define HH 4
#define KK 3
#define HDh 32
#define NN (BB*TT)
#define NPOS 9
#define NCH 16
#define CHL (TT/NCH)

__device__ __forceinline__ float gelu_exact(float v) {
    return 0.5f * v * (1.0f + erff(v * 0.70710678118654752440f));
}

// ---------------- K1: per-batch column mean of x ----------------
__global__ __launch_bounds__(256) void k1a(const float* __restrict__ x, float* __restrict__ partial) {
    int d = blockIdx.x * 256 + threadIdx.x;
    int b = blockIdx.y, c = blockIdx.z;
    const float* xp = x + ((size_t)b * TT + (size_t)c * CHL) * DD + d;
    float s = 0.0f;
    for (int t = 0; t < CHL; t++) s += xp[(size_t)t * DD];
    partial[(b * NCH + c) * DD + d] = s;
}

__global__ __launch_bounds__(256) void k1b(const float* __restrict__ partial, float* __restrict__ mean_x) {
    int d = blockIdx.x * 256 + threadIdx.x;
    int b = blockIdx.y;
    float s = 0.0f;
    for (int c = 0; c < NCH; c++) s += partial[(b * NCH + c) * DD + d];
    mean_x[b * DD + d] = s * (1.0f / TT);
}

// ---------------- K2: per-batch gctx + rq chain ----------------
__global__ __launch_bounds__(128) void k2_batch(
    const float* __restrict__ mean_x,
    const float* __restrict__ gpw, const float* __restrict__ gpb,
    const float* __restrict__ rq1w, const float* __restrict__ rq1b,
    const float* __restrict__ lnw, const float* __restrict__ lnb,
    const float* __restrict__ rq2w, const float* __restrict__ rq2b,
    float* __restrict__ gctx, float* __restrict__ rqv)
{
    int b = blockIdx.x, d = threadIdx.x;
    __shared__ __attribute__((aligned(16))) float g[DLb];
    __shared__ __attribute__((aligned(16))) float t1[DLb];
    __shared__ __attribute__((aligned(16))) float act[DLb];
    __shared__ float red[2];

    // gctx[d] = mean_x[b] . gpw[d] + gpb[d]
    {
        const float4* wrow = (const float4*)(gpw + (size_t)d * DD);
        const float4* mx4  = (const float4*)(mean_x + (size_t)b * DD);
        float s = gpb[d];
        for (int k = 0; k < DD / 4; k++) {
            float4 w = wrow[k], m = mx4[k];
            s += w.x * m.x + w.y * m.y + w.z * m.z + w.w * m.w;
        }
        g[d] = s;
        gctx[b * DLb + d] = s;
    }
    __syncthreads();
    // t1 = g @ rq1w^T + rq1b
    {
        float s = rq1b[d];
        for (int k = 0; k < DLb; k++) s += g[k] * rq1w[d * DLb + k];
        t1[d] = s;
    }
    __syncthreads();
    if (d == 0) {
        float m = 0.0f;
        for (int i = 0; i < DLb; i++) m += t1[i];
        m *= (1.0f / DLb);
        float v = 0.0f;
        for (int i = 0; i < DLb; i++) { float df = t1[i] - m; v += df * df; }
        v *= (1.0f / DLb);
        red[0] = m; red[1] = 1.0f / sqrtf(v + 1e-5f);
    }
    __syncthreads();
    {
        float xn = (t1[d] - red[0]) * red[1] * lnw[d] + lnb[d];
        act[d] = gelu_exact(xn);
    }
    __syncthreads();
    {
        float s = rq2b[d];
        for (int k = 0; k < DLb; k++) s += act[k] * rq2w[d * DLb + k];
        rqv[b * DLb + d] = s;
    }
}

// ---------------- K3: ef = X @ W_down^T (fp32 tiled GEMM) ----------------
// C[n][j] = sum_k A[n][k] * W[j][k];  M=NN, K=DD, N=EE*DLb (all 1024-mult)
__global__ __launch_bounds__(256) void k3_gemm(const float* __restrict__ A,
                                               const float* __restrict__ W,
                                               float* __restrict__ C)
{
    __shared__ __attribute__((aligned(16))) float As[16][68];
    __shared__ __attribute__((aligned(16))) float Bs[16][68];
    int tid = threadIdx.x;
    int tx = tid & 15, ty = tid >> 4;
    int row0 = blockIdx.y * 64, col0 = blockIdx.x * 64;
    int lr = tid >> 2, lk = (tid & 3) * 4;
    float acc[4][4] = {};
    for (int k0 = 0; k0 < DD; k0 += 16) {
        float4 a4 = *(const float4*)&A[(size_t)(row0 + lr) * DD + k0 + lk];
        float4 b4 = *(const float4*)&W[(size_t)(col0 + lr) * DD + k0 + lk];
        As[lk + 0][lr] = a4.x; As[lk + 1][lr] = a4.y; As[lk + 2][lr] = a4.z; As[lk + 3][lr] = a4.w;
        Bs[lk + 0][lr] = b4.x; Bs[lk + 1][lr] = b4.y; Bs[lk + 2][lr] = b4.z; Bs[lk + 3][lr] = b4.w;
        __syncthreads();
        #pragma unroll
        for (int kk = 0; kk < 16; kk++) {
            float4 a = *(const float4*)&As[kk][ty * 4];
            float4 bvv = *(const float4*)&Bs[kk][tx * 4];
            float av[4] = {a.x, a.y, a.z, a.w};
            float bv[4] = {bvv.x, bvv.y, bvv.z, bvv.w};
            #pragma unroll
            for (int i = 0; i < 4; i++)
                #pragma unroll
                for (int j = 0; j < 4; j++)
                    acc[i][j] += av[i] * bv[j];
        }
        __syncthreads();
    }
    #pragma unroll
    for (int i = 0; i < 4; i++) {
        float4 o; o.x = acc[i][0]; o.y = acc[i][1]; o.z = acc[i][2]; o.w = acc[i][3];
        *(float4*)&C[(size_t)(row0 + ty * 4 + i) * (EE * DLb) + col0 + tx * 4] = o;
    }
}

// ---------------- K4: per-token attention + LN + router ----------------
__global__ __launch_bounds__(256) void k4_token(
    const float* __restrict__ ef, const float* __restrict__ gctx,
    const float* __restrict__ pe,
    const float* __restrict__ aiw, const float* __restrict__ aib,
    const float* __restrict__ aow, const float* __restrict__ aob,
    const float* __restrict__ nw, const float* __restrict__ nb,
    const float* __restrict__ rkw, const float* __restrict__ rkb,
    const float* __restrict__ rqv,
    float* __restrict__ probs, float* __restrict__ wsel)
{
    int n = blockIdx.x;
    int b = n / TT;
    int tid = threadIdx.x;
    __shared__ __attribute__((aligned(16))) float seq[NPOS][DLb];
    __shared__ __attribute__((aligned(16))) float qkv[NPOS][3 * DLb];
    __shared__ __attribute__((aligned(16))) float ov[NPOS][DLb];
    __shared__ __attribute__((aligned(16))) float s2[NPOS][DLb];
    __shared__ float attnw[HH * NPOS][12];
    __shared__ float mvs[NPOS][2];
    __shared__ float lg[EE];

    // 1. build seq (row 0 = gctx, rows 1..8 = ef + pos_embed)
    for (int i = tid; i < NPOS * DLb; i += 256) {
        int p = i >> 7, d = i & 127;
        seq[p][d] = (p == 0) ? gctx[b * DLb + d]
                             : ef[(size_t)n * (EE * DLb) + (p - 1) * DLb + d] + pe[(p - 1) * DLb + d];
    }
    __syncthreads();

    // 2. qkv = seq @ attn_in_w^T + b   (each thread owns weight row r, loops 9 positions)
    for (int r = tid; r < 3 * DLb; r += 256) {
        float part[NPOS];
        #pragma unroll
        for (int p = 0; p < NPOS; p++) part[p] = 0.0f;
        const float4* w4 = (const float4*)(aiw + (size_t)r * DLb);
        for (int kc = 0; kc < DLb / 4; kc++) {
            float4 w = w4[kc];
            #pragma unroll
            for (int p = 0; p < NPOS; p++) {
                float4 xv = *(const float4*)&seq[p][kc * 4];
                part[p] += w.x * xv.x + w.y * xv.y + w.z * xv.z + w.w * xv.w;
            }
        }
        float bia = aib[r];
        #pragma unroll
        for (int p = 0; p < NPOS; p++) qkv[p][r] = part[p] + bia;
    }
    __syncthreads();

    // 3. attention scores + softmax (one thread per (head, query))
    if (tid < HH * NPOS) {
        int h = tid / NPOS, i = tid % NPOS;
        float sc[NPOS];
        float mx = -1e30f;
        for (int j = 0; j < NPOS; j++) {
            float s = 0.0f;
            for (int d2 = 0; d2 < HDh; d2++)
                s += qkv[i][h * HDh + d2] * qkv[j][DLb + h * HDh + d2];
            s *= 0.17677669529663687f;  // 1/sqrt(32)
            sc[j] = s;
            mx = fmaxf(mx, s);
        }
        float se = 0.0f;
        for (int j = 0; j < NPOS; j++) { sc[j] = expf(sc[j] - mx); se += sc[j]; }
        float inv = 1.0f / se;
        for (int j = 0; j < NPOS; j++) attnw[tid][j] = sc[j] * inv;
    }
    __syncthreads();

    // o = attn @ v
    for (int i = tid; i < NPOS * DLb; i += 256) {
        int p = i >> 7, d = i & 127, h = d >> 5;
        float s = 0.0f;
        #pragma unroll
        for (int j = 0; j < NPOS; j++) s += attnw[h * NPOS + p][j] * qkv[j][2 * DLb + d];
        ov[p][d] = s;
    }
    __syncthreads();

    // 4. attn_out + residual
    if (tid < DLb) {
        int d = tid;
        float part[NPOS];
        #pragma unroll
        for (int p = 0; p < NPOS; p++) part[p] = 0.0f;
        const float4* w4 = (const float4*)(aow + (size_t)d * DLb);
        for (int kc = 0; kc < DLb / 4; kc++) {
            float4 w = w4[kc];
            #pragma unroll
            for (int p = 0; p < NPOS; p++) {
                float4 xv = *(const float4*)&ov[p][kc * 4];
                part[p] += w.x * xv.x + w.y * xv.y + w.z * xv.z + w.w * xv.w;
            }
        }
        float bia = aob[d];
        #pragma unroll
        for (int p = 0; p < NPOS; p++) s2[p][d] = part[p] + bia + seq[p][d];
    }
    __syncthreads();

    // 5. LayerNorm rows
    if (tid < NPOS) {
        float m = 0.0f;
        for (int d2 = 0; d2 < DLb; d2++) m += s2[tid][d2];
        m *= (1.0f / DLb);
        float v = 0.0f;
        for (int d2 = 0; d2 < DLb; d2++) { float df = s2[tid][d2] - m; v += df * df; }
        v *= (1.0f / DLb);
        mvs[tid][0] = m;
        mvs[tid][1] = 1.0f / sqrtf(v + 1e-5f);
    }
    __syncthreads();
    for (int i = tid; i < NPOS * DLb; i += 256) {
        int p = i >> 7, d = i & 127;
        s2[p][d] = (s2[p][d] - mvs[p][0]) * mvs[p][1] * nw[d] + nb[d];
    }
    __syncthreads();

    // 6. rk = refined @ rk_w^T + rk_b  (into ov[e][d])
    if (tid < DLb) {
        int d = tid;
        float part[EE];
        #pragma unroll
        for (int e = 0; e < EE; e++) part[e] = 0.0f;
        const float4* w4 = (const float4*)(rkw + (size_t)d * DLb);
        for (int kc = 0; kc < DLb / 4; kc++) {
            float4 w = w4[kc];
            #pragma unroll
            for (int e = 0; e < EE; e++) {
                float4 xv = *(const float4*)&s2[1 + e][kc * 4];
                part[e] += w.x * xv.x + w.y * xv.y + w.z * xv.z + w.w * xv.w;
            }
        }
        float bia = rkb[d];
        #pragma unroll
        for (int e = 0; e < EE; e++) ov[e][d] = part[e] + bia;
    }
    __syncthreads();

    // logits
    if (tid < EE) {
        const float* rqp = rqv + b * DLb;
        float s = 0.0f;
        for (int d2 = 0; d2 < DLb; d2++) s += rqp[d2] * ov[tid][d2];
        lg[tid] = s * 0.08838834764831845f;  // 1/sqrt(128)
    }
    __syncthreads();

    // 7. softmax + top-3 + normalized weights
    if (tid == 0) {
        float mx = lg[0];
        for (int e = 1; e < EE; e++) mx = fmaxf(mx, lg[e]);
        float pr[EE];
        float se = 0.0f;
        for (int e = 0; e < EE; e++) { pr[e] = expf(lg[e] - mx); se += pr[e]; }
        float inv = 1.0f / se;
        for (int e = 0; e < EE; e++) {
            pr[e] *= inv;
            probs[(size_t)n * EE + e] = pr[e];
        }
        bool used[EE] = {};
        int sel[KK];
        float sw = 0.0f;
        for (int t = 0; t < KK; t++) {
            int bi = 0; float bv = -1e30f;
            for (int e = 0; e < EE; e++)
                if (!used[e] && pr[e] > bv) { bv = pr[e]; bi = e; }
            used[bi] = true; sel[t] = bi; sw += pr[bi];
        }
        float invsw = 1.0f / sw;
        float w8[EE];
        for (int e = 0; e < EE; e++) w8[e] = 0.0f;
        for (int t = 0; t < KK; t++) w8[sel[t]] = pr[sel[t]] * invsw;
        for (int e = 0; e < EE; e++) wsel[(size_t)n * EE + e] = w8[e];
    }
}

// ---------------- K5: weighted = (wsel * gelu(ef)) @ w_up_flat ----------------
// C[n][m] = sum_k wsel[n][k>>7]*gelu(ef[n][k]) * WUP[k][m]
__global__ __launch_bounds__(256) void k5_gemm(const float* __restrict__ EF,
                                               const float* __restrict__ WSEL,
                                               const float* __restrict__ WUP,
                                               float* __restrict__ C)
{
    __shared__ __attribute__((aligned(16))) float As[16][68];
    __shared__ __attribute__((aligned(16))) float Bs[16][68];
    int tid = threadIdx.x;
    int tx = tid & 15, ty = tid >> 4;
    int row0 = blockIdx.y * 64, col0 = blockIdx.x * 64;
    int lr = tid >> 2, lk = (tid & 3) * 4;   // A-tile load coords
    int kr = tid >> 4, cc = tid & 15;        // B-tile load coords
    float acc[4][4] = {};
    for (int k0 = 0; k0 < EE * DLb; k0 += 16) {
        float4 a4 = *(const float4*)&EF[(size_t)(row0 + lr) * (EE * DLb) + k0 + lk];
        int e = (k0 + lk) >> 7;
        float w = WSEL[(size_t)(row0 + lr) * EE + e];
        a4.x = w * gelu_exact(a4.x);
        a4.y = w * gelu_exact(a4.y);
        a4.z = w * gelu_exact(a4.z);
        a4.w = w * gelu_exact(a4.w);
        float4 b4 = *(const float4*)&WUP[(size_t)(k0 + kr) * DD + col0 + cc * 4];
        As[lk + 0][lr] = a4.x; As[lk + 1][lr] = a4.y; As[lk + 2][lr] = a4.z; As[lk + 3][lr] = a4.w;
        *(float4*)&Bs[kr][cc * 4] = b4;
        __syncthreads();
        #pragma unroll
        for (int kk = 0; kk < 16; kk++) {
            float4 a = *(const float4*)&As[kk][ty * 4];
            float4 bvv = *(const float4*)&Bs[kk][tx * 4];
            float av[4] = {a.x, a.y, a.z, a.w};
            float bv[4] = {bvv.x, bvv.y, bvv.z, bvv.w};
            #pragma unroll
            for (int i = 0; i < 4; i++)
                #pragma unroll
                for (int j = 0; j < 4; j++)
                    acc[i][j] += av[i] * bv[j];
        }
        __syncthreads();
    }
    #pragma unroll
    for (int i = 0; i < 4; i++) {
        float4 o; o.x = acc[i][0]; o.y = acc[i][1]; o.z = acc[i][2]; o.w = acc[i][3];
        *(float4*)&C[(size_t)(row0 + ty * 4 + i) * DD + col0 + tx * 4] = o;
    }
}

// ---------------- K6: aux loss (deterministic reduction) ----------------
__global__ __launch_bounds__(256) void k6_aux(const float* __restrict__ probs,
                                              const float* __restrict__ wsel,
                                              float* __restrict__ out_aux)
{
    int tid = threadIdx.x;
    float lp[EE], lc[EE];
    #pragma unroll
    for (int e = 0; e < EE; e++) { lp[e] = 0.0f; lc[e] = 0.0f; }
    for (int n = tid; n < NN; n += 256) {
        #pragma unroll
        for (int e = 0; e < EE; e++) {
            lp[e] += probs[(size_t)n * EE + e];
            lc[e] += (wsel[(size_t)n * EE + e] > 0.0f) ? 1.0f : 0.0f;
        }
    }
    __shared__ float bp[256][EE];
    __shared__ float bc[256][EE];
    #pragma unroll
    for (int e = 0; e < EE; e++) { bp[tid][e] = lp[e]; bc[tid][e] = lc[e]; }
    __syncthreads();
    for (int s = 128; s > 0; s >>= 1) {
        if (tid < s) {
            #pragma unroll
            for (int e = 0; e < EE; e++) {
                bp[tid][e] += bp[tid + s][e];
                bc[tid][e] += bc[tid + s][e];
            }
        }
        __syncthreads();
    }
    if (tid == 0) {
        float a = 0.0f;
        for (int e = 0; e < EE; e++) a += (bp[0][e] / NN) * (bc[0][e] / NN);
        out_aux[0] = EE * a;
    }
}

extern "C" void kernel_launch(void* const* d_in, const int* in_sizes, int n_in,
                              void* d_out, int out_size, void* d_ws, size_t ws_size,
                              hipStream_t stream) {
    const float* x     = (const float*)d_in[0];
    const float* wdown = (const float*)d_in[1];
    const float* pe    = (const float*)d_in[2];
    const float* gpw   = (const float*)d_in[3];
    const float* gpb   = (const float*)d_in[4];
    const float* aiw   = (const float*)d_in[5];
    const float* aib   = (const float*)d_in[6];
    const float* aow   = (const float*)d_in[7];
    const float* aob   = (const float*)d_in[8];
    const float* nw    = (const float*)d_in[9];
    const float* nb    = (const float*)d_in[10];
    const float* rq1w  = (const float*)d_in[11];
    const float* rq1b  = (const float*)d_in[12];
    const float* rqlnw = (const float*)d_in[13];
    const float* rqlnb = (const float*)d_in[14];
    const float* rq2w  = (const float*)d_in[15];
    const float* rq2b  = (const float*)d_in[16];
    const float* rkw   = (const float*)d_in[17];
    const float* rkb   = (const float*)d_in[18];
    const float* wup   = (const float*)d_in[19];

    float* out = (float*)d_out;

    float* ef      = (float*)d_ws;                       // NN * EE*DLb = 8,388,608
    float* partial = ef + (size_t)NN * EE * DLb;         // BB*NCH*DD  = 65,536
    float* mean_x  = partial + (size_t)BB * NCH * DD;    // BB*DD      = 4,096
    float* gctx    = mean_x + (size_t)BB * DD;           // BB*DLb     = 512
    float* rqv     = gctx + (size_t)BB * DLb;            // BB*DLb     = 512
    float* probs   = rqv + (size_t)BB * DLb;             // NN*EE      = 65,536
    float* wsel    = probs + (size_t)NN * EE;            // NN*EE      = 65,536

    hipLaunchKernelGGL(k1a, dim3(DD / 256, BB, NCH), dim3(256), 0, stream, x, partial);
    hipLaunchKernelGGL(k1b, dim3(DD / 256, BB), dim3(256), 0, stream, partial, mean_x);
    hipLaunchKernelGGL(k2_batch, dim3(BB), dim3(DLb), 0, stream,
                       mean_x, gpw, gpb, rq1w, rq1b, rqlnw, rqlnb, rq2w, rq2b, gctx, rqv);
    hipLaunchKernelGGL(k3_gemm, dim3((EE * DLb) / 64, NN / 64), dim3(256), 0, stream, x, wdown, ef);
    hipLaunchKernelGGL(k4_token, dim3(NN), dim3(256), 0, stream,
                       ef, gctx, pe, aiw, aib, aow, aob, nw, nb, rkw, rkb, rqv, probs, wsel);
    hipLaunchKernelGGL(k5_gemm, dim3(DD / 64, NN / 64), dim3(256), 0, stream, ef, wsel, wup, out);
    hipLaunchKernelGGL(k6_aux, dim3(1), dim3(256), 0, stream, probs, wsel, out + (size_t)NN * DD);
}

// Round 2
// 1053.304 us; speedup vs baseline: 1.0057x; 1.0057x over previous
//
#include <hip/hip_runtime.h>
#include <hip/hip_bf16.h>
#include <math.h>

#define BB 4
#define TT 2048
#define DD 1024
#define DLb 128
#define EE 8
#define HH 4
#define KK 3
#define HDh 32
#define NN (BB*TT)
#define NPOS 9
#define NCH 16
#define CHL (TT/NCH)
#define SEQSTR (NPOS*DLb)   // 1152

typedef __attribute__((ext_vector_type(8))) short short8;
typedef __attribute__((ext_vector_type(4))) float f32x4;
typedef __attribute__((ext_vector_type(8))) unsigned short ushort8;

__device__ __forceinline__ float gelu_exact(float v) {
    return 0.5f * v * (1.0f + erff(v * 0.70710678118654752440f));
}

__device__ __forceinline__ unsigned short f2bf(float x) {
    __hip_bfloat16 h = __float2bfloat16(x);
    return *reinterpret_cast<unsigned short*>(&h);
}

// ---------------- K1: per-batch column mean of x ----------------
__global__ __launch_bounds__(256) void k1a(const float* __restrict__ x, float* __restrict__ partial) {
    int d = blockIdx.x * 256 + threadIdx.x;
    int b = blockIdx.y, c = blockIdx.z;
    const float* xp = x + ((size_t)b * TT + (size_t)c * CHL) * DD + d;
    float s = 0.0f;
    for (int t = 0; t < CHL; t++) s += xp[(size_t)t * DD];
    partial[(b * NCH + c) * DD + d] = s;
}

__global__ __launch_bounds__(256) void k1b(const float* __restrict__ partial, float* __restrict__ mean_x) {
    int d = blockIdx.x * 256 + threadIdx.x;
    int b = blockIdx.y;
    float s = 0.0f;
    for (int c = 0; c < NCH; c++) s += partial[(b * NCH + c) * DD + d];
    mean_x[b * DD + d] = s * (1.0f / TT);
}

// ---------------- K2: per-batch gctx + rq chain ----------------
__global__ __launch_bounds__(128) void k2_batch(
    const float* __restrict__ mean_x,
    const float* __restrict__ gpw, const float* __restrict__ gpb,
    const float* __restrict__ rq1w, const float* __restrict__ rq1b,
    const float* __restrict__ lnw, const float* __restrict__ lnb,
    const float* __restrict__ rq2w, const float* __restrict__ rq2b,
    float* __restrict__ gctx, float* __restrict__ rqv)
{
    int b = blockIdx.x, d = threadIdx.x;
    __shared__ __attribute__((aligned(16))) float g[DLb];
    __shared__ __attribute__((aligned(16))) float t1[DLb];
    __shared__ __attribute__((aligned(16))) float act[DLb];
    __shared__ float red[2];
    {
        const float4* wrow = (const float4*)(gpw + (size_t)d * DD);
        const float4* mx4  = (const float4*)(mean_x + (size_t)b * DD);
        float s = gpb[d];
        for (int k = 0; k < DD / 4; k++) {
            float4 w = wrow[k], m = mx4[k];
            s += w.x * m.x + w.y * m.y + w.z * m.z + w.w * m.w;
        }
        g[d] = s;
        gctx[b * DLb + d] = s;
    }
    __syncthreads();
    {
        float s = rq1b[d];
        for (int k = 0; k < DLb; k++) s += g[k] * rq1w[d * DLb + k];
        t1[d] = s;
    }
    __syncthreads();
    if (d == 0) {
        float m = 0.0f;
        for (int i = 0; i < DLb; i++) m += t1[i];
        m *= (1.0f / DLb);
        float v = 0.0f;
        for (int i = 0; i < DLb; i++) { float df = t1[i] - m; v += df * df; }
        v *= (1.0f / DLb);
        red[0] = m; red[1] = 1.0f / sqrtf(v + 1e-5f);
    }
    __syncthreads();
    {
        float xn = (t1[d] - red[0]) * red[1] * lnw[d] + lnb[d];
        act[d] = gelu_exact(xn);
    }
    __syncthreads();
    {
        float s = rq2b[d];
        for (int k = 0; k < DLb; k++) s += act[k] * rq2w[d * DLb + k];
        rqv[b * DLb + d] = s;
    }
}

// ---------------- K2b: fill seq position 0 with gctx ----------------
__global__ __launch_bounds__(256) void k2b(const float* __restrict__ gctx, float* __restrict__ seq) {
    int i = blockIdx.x * 256 + threadIdx.x;   // over NN*DLb
    int n = i >> 7, d = i & 127;
    seq[(size_t)n * SEQSTR + d] = gctx[(n >> 11) * DLb + d];
}

// ---------------- K3: seq[:,1:,:] = x @ w_down^T + pe (fp32 128x128 tile) ----------------
__global__ __launch_bounds__(256) void k3_gemm(const float* __restrict__ A,
                                               const float* __restrict__ W,
                                               const float* __restrict__ pe,
                                               float* __restrict__ seq)
{
    __shared__ __attribute__((aligned(16))) float As[16][132];
    __shared__ __attribute__((aligned(16))) float Bs[16][132];
    int tid = threadIdx.x;
    int tx = tid & 15, ty = tid >> 4;
    int row0 = blockIdx.y * 128, col0 = blockIdx.x * 128;
    float acc[8][8] = {};
    for (int k0 = 0; k0 < DD; k0 += 16) {
        #pragma unroll
        for (int i = 0; i < 2; i++) {
            int L = i * 256 + tid;
            int r = L >> 2, kq = (L & 3) * 4;
            float4 a4 = *(const float4*)&A[(size_t)(row0 + r) * DD + k0 + kq];
            float4 b4 = *(const float4*)&W[(size_t)(col0 + r) * DD + k0 + kq];
            As[kq + 0][r] = a4.x; As[kq + 1][r] = a4.y; As[kq + 2][r] = a4.z; As[kq + 3][r] = a4.w;
            Bs[kq + 0][r] = b4.x; Bs[kq + 1][r] = b4.y; Bs[kq + 2][r] = b4.z; Bs[kq + 3][r] = b4.w;
        }
        __syncthreads();
        #pragma unroll
        for (int kk = 0; kk < 16; kk++) {
            float4 a0 = *(const float4*)&As[kk][ty * 4];
            float4 a1 = *(const float4*)&As[kk][64 + ty * 4];
            float4 b0 = *(const float4*)&Bs[kk][tx * 4];
            float4 b1 = *(const float4*)&Bs[kk][64 + tx * 4];
            float ar[8] = {a0.x, a0.y, a0.z, a0.w, a1.x, a1.y, a1.z, a1.w};
            float bc[8] = {b0.x, b0.y, b0.z, b0.w, b1.x, b1.y, b1.z, b1.w};
            #pragma unroll
            for (int i = 0; i < 8; i++)
                #pragma unroll
                for (int j = 0; j < 8; j++)
                    acc[i][j] += ar[i] * bc[j];
        }
        __syncthreads();
    }
    float4 pe0 = *(const float4*)&pe[col0 + tx * 4];
    float4 pe1 = *(const float4*)&pe[col0 + 64 + tx * 4];
    #pragma unroll
    for (int i = 0; i < 8; i++) {
        int gr = row0 + ((i < 4) ? (ty * 4 + i) : (64 + ty * 4 + (i - 4)));
        float* dst = seq + (size_t)gr * SEQSTR + DLb + col0;
        float4 o0; o0.x = acc[i][0] + pe0.x; o0.y = acc[i][1] + pe0.y; o0.z = acc[i][2] + pe0.z; o0.w = acc[i][3] + pe0.w;
        float4 o1; o1.x = acc[i][4] + pe1.x; o1.y = acc[i][5] + pe1.y; o1.z = acc[i][6] + pe1.z; o1.w = acc[i][7] + pe1.w;
        *(float4*)&dst[tx * 4] = o0;
        *(float4*)&dst[64 + tx * 4] = o1;
    }
}

// ---------------- K4: per-token attention + LN + router (register-tiled) ----------------
__global__ __launch_bounds__(256) void k4_token(
    const float* __restrict__ seqg,
    const float* __restrict__ aiw, const float* __restrict__ aib,
    const float* __restrict__ aow, const float* __restrict__ aob,
    const float* __restrict__ nw, const float* __restrict__ nb,
    const float* __restrict__ rkw, const float* __restrict__ rkb,
    const float* __restrict__ rqv,
    float* __restrict__ probs, float* __restrict__ wsel)
{
    int n = blockIdx.x;
    int b = n >> 11;
    int tid = threadIdx.x;
    __shared__ __attribute__((aligned(16))) float sseq[NPOS][DLb];
    __shared__ __attribute__((aligned(16))) float qkv[NPOS][3 * DLb];
    __shared__ __attribute__((aligned(16))) float ovs[NPOS][DLb];
    __shared__ __attribute__((aligned(16))) float s2s[NPOS][DLb];
    __shared__ float attnw[HH * NPOS][12];
    __shared__ float mvs[NPOS][2];
    __shared__ float lg[EE];

    // 1. load seq token (9*128 = 288 float4)
    {
        const float4* src = (const float4*)(seqg + (size_t)n * SEQSTR);
        float4* dst = (float4*)&sseq[0][0];
        for (int i = tid; i < NPOS * DLb / 4; i += 256) dst[i] = src[i];
    }
    __syncthreads();

    // 2. qkv: 4 rows/thread x 9 positions (threads 0..95); seq reads are wave-broadcast
    if (tid < 96) {
        int r0 = tid * 4;
        float acc[4][NPOS];
        #pragma unroll
        for (int i = 0; i < 4; i++)
            #pragma unroll
            for (int p = 0; p < NPOS; p++) acc[i][p] = 0.0f;
        for (int kc = 0; kc < DLb / 4; kc++) {
            float4 w0 = *(const float4*)&aiw[(size_t)(r0 + 0) * DLb + kc * 4];
            float4 w1 = *(const float4*)&aiw[(size_t)(r0 + 1) * DLb + kc * 4];
            float4 w2 = *(const float4*)&aiw[(size_t)(r0 + 2) * DLb + kc * 4];
            float4 w3 = *(const float4*)&aiw[(size_t)(r0 + 3) * DLb + kc * 4];
            #pragma unroll
            for (int p = 0; p < NPOS; p++) {
                float4 s = *(const float4*)&sseq[p][kc * 4];
                acc[0][p] += w0.x * s.x + w0.y * s.y + w0.z * s.z + w0.w * s.w;
                acc[1][p] += w1.x * s.x + w1.y * s.y + w1.z * s.z + w1.w * s.w;
                acc[2][p] += w2.x * s.x + w2.y * s.y + w2.z * s.z + w2.w * s.w;
                acc[3][p] += w3.x * s.x + w3.y * s.y + w3.z * s.z + w3.w * s.w;
            }
        }
        float4 bia = *(const float4*)&aib[r0];
        #pragma unroll
        for (int p = 0; p < NPOS; p++) {
            float4 o; o.x = acc[0][p] + bia.x; o.y = acc[1][p] + bia.y;
            o.z = acc[2][p] + bia.z; o.w = acc[3][p] + bia.w;
            *(float4*)&qkv[p][r0] = o;
        }
    }
    __syncthreads();

    // 3. attention scores + softmax
    if (tid < HH * NPOS) {
        int h = tid / NPOS, i = tid % NPOS;
        float sc[NPOS];
        float mx = -1e30f;
        for (int j = 0; j < NPOS; j++) {
            float s = 0.0f;
            for (int d2 = 0; d2 < HDh; d2++)
                s += qkv[i][h * HDh + d2] * qkv[j][DLb + h * HDh + d2];
            s *= 0.17677669529663687f;
            sc[j] = s;
            mx = fmaxf(mx, s);
        }
        float se = 0.0f;
        for (int j = 0; j < NPOS; j++) { sc[j] = expf(sc[j] - mx); se += sc[j]; }
        float inv = 1.0f / se;
        for (int j = 0; j < NPOS; j++) attnw[tid][j] = sc[j] * inv;
    }
    __syncthreads();

    // o = attn @ v
    for (int i = tid; i < NPOS * DLb; i += 256) {
        int p = i >> 7, d = i & 127, h = d >> 5;
        float s = 0.0f;
        #pragma unroll
        for (int j = 0; j < NPOS; j++) s += attnw[h * NPOS + p][j] * qkv[j][2 * DLb + d];
        ovs[p][d] = s;
    }
    __syncthreads();

    // 4. attn_out + residual: 4 cols/thread x 9 positions (threads 0..31)
    if (tid < 32) {
        int c0 = tid * 4;
        float acc[4][NPOS];
        #pragma unroll
        for (int i = 0; i < 4; i++)
            #pragma unroll
            for (int p = 0; p < NPOS; p++) acc[i][p] = 0.0f;
        for (int kc = 0; kc < DLb / 4; kc++) {
            float4 w0 = *(const float4*)&aow[(size_t)(c0 + 0) * DLb + kc * 4];
            float4 w1 = *(const float4*)&aow[(size_t)(c0 + 1) * DLb + kc * 4];
            float4 w2 = *(const float4*)&aow[(size_t)(c0 + 2) * DLb + kc * 4];
            float4 w3 = *(const float4*)&aow[(size_t)(c0 + 3) * DLb + kc * 4];
            #pragma unroll
            for (int p = 0; p < NPOS; p++) {
                float4 s = *(const float4*)&ovs[p][kc * 4];
                acc[0][p] += w0.x * s.x + w0.y * s.y + w0.z * s.z + w0.w * s.w;
                acc[1][p] += w1.x * s.x + w1.y * s.y + w1.z * s.z + w1.w * s.w;
                acc[2][p] += w2.x * s.x + w2.y * s.y + w2.z * s.z + w2.w * s.w;
                acc[3][p] += w3.x * s.x + w3.y * s.y + w3.z * s.z + w3.w * s.w;
            }
        }
        float4 bia = *(const float4*)&aob[c0];
        #pragma unroll
        for (int p = 0; p < NPOS; p++) {
            float4 r = *(const float4*)&sseq[p][c0];
            float4 o; o.x = acc[0][p] + bia.x + r.x; o.y = acc[1][p] + bia.y + r.y;
            o.z = acc[2][p] + bia.z + r.z; o.w = acc[3][p] + bia.w + r.w;
            *(float4*)&s2s[p][c0] = o;
        }
    }
    __syncthreads();

    // 5. LayerNorm rows
    if (tid < NPOS) {
        float m = 0.0f;
        for (int d2 = 0; d2 < DLb; d2++) m += s2s[tid][d2];
        m *= (1.0f / DLb);
        float v = 0.0f;
        for (int d2 = 0; d2 < DLb; d2++) { float df = s2s[tid][d2] - m; v += df * df; }
        v *= (1.0f / DLb);
        mvs[tid][0] = m;
        mvs[tid][1] = 1.0f / sqrtf(v + 1e-5f);
    }
    __syncthreads();
    for (int i = tid; i < NPOS * DLb; i += 256) {
        int p = i >> 7, d = i & 127;
        s2s[p][d] = (s2s[p][d] - mvs[p][0]) * mvs[p][1] * nw[d] + nb[d];
    }
    __syncthreads();

    // 6. rk: 4 cols/thread x 8 experts (threads 0..31), result into ovs[e][*]
    if (tid < 32) {
        int c0 = tid * 4;
        float acc[4][EE];
        #pragma unroll
        for (int i = 0; i < 4; i++)
            #pragma unroll
            for (int e = 0; e < EE; e++) acc[i][e] = 0.0f;
        for (int kc = 0; kc < DLb / 4; kc++) {
            float4 w0 = *(const float4*)&rkw[(size_t)(c0 + 0) * DLb + kc * 4];
            float4 w1 = *(const float4*)&rkw[(size_t)(c0 + 1) * DLb + kc * 4];
            float4 w2 = *(const float4*)&rkw[(size_t)(c0 + 2) * DLb + kc * 4];
            float4 w3 = *(const float4*)&rkw[(size_t)(c0 + 3) * DLb + kc * 4];
            #pragma unroll
            for (int e = 0; e < EE; e++) {
                float4 s = *(const float4*)&s2s[1 + e][kc * 4];
                acc[0][e] += w0.x * s.x + w0.y * s.y + w0.z * s.z + w0.w * s.w;
                acc[1][e] += w1.x * s.x + w1.y * s.y + w1.z * s.z + w1.w * s.w;
                acc[2][e] += w2.x * s.x + w2.y * s.y + w2.z * s.z + w2.w * s.w;
                acc[3][e] += w3.x * s.x + w3.y * s.y + w3.z * s.z + w3.w * s.w;
            }
        }
        float4 bia = *(const float4*)&rkb[c0];
        #pragma unroll
        for (int e = 0; e < EE; e++) {
            float4 o; o.x = acc[0][e] + bia.x; o.y = acc[1][e] + bia.y;
            o.z = acc[2][e] + bia.z; o.w = acc[3][e] + bia.w;
            *(float4*)&ovs[e][c0] = o;
        }
    }
    __syncthreads();

    // logits
    if (tid < EE) {
        const float* rqp = rqv + b * DLb;
        float s = 0.0f;
        for (int d2 = 0; d2 < DLb; d2++) s += rqp[d2] * ovs[tid][d2];
        lg[tid] = s * 0.08838834764831845f;
    }
    __syncthreads();

    // 7. softmax + top-3 + normalized weights
    if (tid == 0) {
        float mx = lg[0];
        for (int e = 1; e < EE; e++) mx = fmaxf(mx, lg[e]);
        float pr[EE];
        float se = 0.0f;
        for (int e = 0; e < EE; e++) { pr[e] = expf(lg[e] - mx); se += pr[e]; }
        float inv = 1.0f / se;
        for (int e = 0; e < EE; e++) {
            pr[e] *= inv;
            probs[(size_t)n * EE + e] = pr[e];
        }
        bool used[EE] = {};
        int sel[KK];
        float sw = 0.0f;
        for (int t = 0; t < KK; t++) {
            int bi = 0; float bv = -1e30f;
            for (int e = 0; e < EE; e++)
                if (!used[e] && pr[e] > bv) { bv = pr[e]; bi = e; }
            used[bi] = true; sel[t] = bi; sw += pr[bi];
        }
        float invsw = 1.0f / sw;
        float w8[EE];
        for (int e = 0; e < EE; e++) w8[e] = 0.0f;
        for (int t = 0; t < KK; t++) w8[sel[t]] = pr[sel[t]] * invsw;
        for (int e = 0; e < EE; e++) wsel[(size_t)n * EE + e] = w8[e];
    }
}

// ---------------- K5pre: a_bf16[n][k] = wsel[n][k>>7] * gelu(seq - pe) ----------------
__global__ __launch_bounds__(256) void k5pre(const float* __restrict__ seq,
                                             const float* __restrict__ pe,
                                             const float* __restrict__ wsel,
                                             unsigned short* __restrict__ abf)
{
    size_t g = ((size_t)blockIdx.x * 256 + threadIdx.x) * 8;   // 8 elements per thread
    int n = (int)(g >> 10), k0 = (int)(g & 1023);
    int e = k0 >> 7;
    float w = wsel[(size_t)n * EE + e];
    const float* sp = seq + (size_t)n * SEQSTR + DLb + k0;
    float4 s0 = *(const float4*)&sp[0];
    float4 s1 = *(const float4*)&sp[4];
    float4 p0 = *(const float4*)&pe[k0];
    float4 p1 = *(const float4*)&pe[k0 + 4];
    float v[8];
    v[0] = w * gelu_exact(s0.x - p0.x); v[1] = w * gelu_exact(s0.y - p0.y);
    v[2] = w * gelu_exact(s0.z - p0.z); v[3] = w * gelu_exact(s0.w - p0.w);
    v[4] = w * gelu_exact(s1.x - p1.x); v[5] = w * gelu_exact(s1.y - p1.y);
    v[6] = w * gelu_exact(s1.z - p1.z); v[7] = w * gelu_exact(s1.w - p1.w);
    ushort8 o;
    #pragma unroll
    for (int i = 0; i < 8; i++) o[i] = f2bf(v[i]);
    *(ushort8*)&abf[g] = o;
}

// ---------------- K5t: wupT[m][k] = bf16(wup[k][m]) ----------------
__global__ __launch_bounds__(256) void k5t(const float* __restrict__ wup, unsigned short* __restrict__ wupT) {
    __shared__ float T[64][68];
    int tid = threadIdx.x;
    int k0 = blockIdx.x * 64, m0 = blockIdx.y * 64;
    #pragma unroll
    for (int i = 0; i < 4; i++) {
        int F = i * 256 + tid;
        int r = F >> 4, c4 = (F & 15) * 4;
        *(float4*)&T[r][c4] = *(const float4*)&wup[(size_t)(k0 + r) * DD + m0 + c4];
    }
    __syncthreads();
    #pragma unroll
    for (int i = 0; i < 2; i++) {
        int W = i * 256 + tid;
        int r = W >> 3, c8 = (W & 7) * 8;
        ushort8 o;
        #pragma unroll
        for (int j = 0; j < 8; j++) o[j] = f2bf(T[c8 + j][r]);
        *(ushort8*)&wupT[(size_t)(m0 + r) * DD + k0 + c8] = o;
    }
}

// ---------------- K5: out = a_bf16 @ wupT^T via MFMA 16x16x32 bf16 ----------------
#define RSA 40   // LDS row stride in bf16 elements (32 data + 8 pad -> 80B, 2-way banks)
__global__ __launch_bounds__(256) void k5_mfma(const unsigned short* __restrict__ A,
                                               const unsigned short* __restrict__ B,
                                               float* __restrict__ C)
{
    __shared__ __attribute__((aligned(16))) unsigned short As[128 * RSA];
    __shared__ __attribute__((aligned(16))) unsigned short Bs[128 * RSA];
    int tid = threadIdx.x;
    int lane = tid & 63, wave = tid >> 6;
    int wm = wave & 1, wn = wave >> 1;            // 2x2 wave grid, each wave 64x64
    int row0 = blockIdx.y * 128, col0 = blockIdx.x * 128;
    int fr = lane & 15, fq = lane >> 4;           // frag row/col idx, k-quad
    f32x4 acc[4][4];
    #pragma unroll
    for (int i = 0; i < 4; i++)
        #pragma unroll
        for (int j = 0; j < 4; j++) acc[i][j] = (f32x4)0.0f;

    for (int k0 = 0; k0 < DD; k0 += 32) {
        #pragma unroll
        for (int i = 0; i < 2; i++) {
            int L = i * 256 + tid;
            int r = L >> 2, q = (L & 3) * 8;
            *(ushort8*)&As[r * RSA + q] = *(const ushort8*)&A[(size_t)(row0 + r) * DD + k0 + q];
            *(ushort8*)&Bs[r * RSA + q] = *(const ushort8*)&B[(size_t)(col0 + r) * DD + k0 + q];
        }
        __syncthreads();
        short8 af[4], bf[4];
        #pragma unroll
        for (int f = 0; f < 4; f++) {
            af[f] = *(const short8*)&As[(wm * 64 + f * 16 + fr) * RSA + fq * 8];
            bf[f] = *(const short8*)&Bs[(wn * 64 + f * 16 + fr) * RSA + fq * 8];
        }
        #pragma unroll
        for (int i = 0; i < 4; i++)
            #pragma unroll
            for (int j = 0; j < 4; j++)
                acc[i][j] = __builtin_amdgcn_mfma_f32_16x16x32_bf16(af[i], bf[j], acc[i][j], 0, 0, 0);
        __syncthreads();
    }
    // D layout: col = lane&15, row = (lane>>4)*4 + reg   [m89-verified]
    #pragma unroll
    for (int i = 0; i < 4; i++) {
        #pragma unroll
        for (int j = 0; j < 4; j++) {
            int gc = col0 + wn * 64 + j * 16 + fr;
            #pragma unroll
            for (int r = 0; r < 4; r++) {
                int gr = row0 + wm * 64 + i * 16 + fq * 4 + r;
                C[(size_t)gr * DD + gc] = acc[i][j][r];
            }
        }
    }
}

// ---------------- K6: aux loss ----------------
__global__ __launch_bounds__(256) void k6_aux(const float* __restrict__ probs,
                                              const float* __restrict__ wsel,
                                              float* __restrict__ out_aux)
{
    int tid = threadIdx.x;
    float lp[EE], lc[EE];
    #pragma unroll
    for (int e = 0; e < EE; e++) { lp[e] = 0.0f; lc[e] = 0.0f; }
    for (int n = tid; n < NN; n += 256) {
        #pragma unroll
        for (int e = 0; e < EE; e++) {
            lp[e] += probs[(size_t)n * EE + e];
            lc[e] += (wsel[(size_t)n * EE + e] > 0.0f) ? 1.0f : 0.0f;
        }
    }
    __shared__ float bp[256][EE];
    __shared__ float bc[256][EE];
    #pragma unroll
    for (int e = 0; e < EE; e++) { bp[tid][e] = lp[e]; bc[tid][e] = lc[e]; }
    __syncthreads();
    for (int s = 128; s > 0; s >>= 1) {
        if (tid < s) {
            #pragma unroll
            for (int e = 0; e < EE; e++) {
                bp[tid][e] += bp[tid + s][e];
                bc[tid][e] += bc[tid + s][e];
            }
        }
        __syncthreads();
    }
    if (tid == 0) {
        float a = 0.0f;
        for (int e = 0; e < EE; e++) a += (bp[0][e] / NN) * (bc[0][e] / NN);
        out_aux[0] = EE * a;
    }
}

extern "C" void kernel_launch(void* const* d_in, const int* in_sizes, int n_in,
                              void* d_out, int out_size, void* d_ws, size_t ws_size,
                              hipStream_t stream) {
    const float* x     = (const float*)d_in[0];
    const float* wdown = (const float*)d_in[1];
    const float* pe    = (const float*)d_in[2];
    const float* gpw   = (const float*)d_in[3];
    const float* gpb   = (const float*)d_in[4];
    const float* aiw   = (const float*)d_in[5];
    const float* aib   = (const float*)d_in[6];
    const float* aow   = (const float*)d_in[7];
    const float* aob   = (const float*)d_in[8];
    const float* nw    = (const float*)d_in[9];
    const float* nb    = (const float*)d_in[10];
    const float* rq1w  = (const float*)d_in[11];
    const float* rq1b  = (const float*)d_in[12];
    const float* rqlnw = (const float*)d_in[13];
    const float* rqlnb = (const float*)d_in[14];
    const float* rq2w  = (const float*)d_in[15];
    const float* rq2b  = (const float*)d_in[16];
    const float* rkw   = (const float*)d_in[17];
    const float* rkb   = (const float*)d_in[18];
    const float* wup   = (const float*)d_in[19];

    float* out = (float*)d_out;

    float* seq     = (float*)d_ws;                         // NN*1152 = 9,437,184
    float* probs   = seq + (size_t)NN * SEQSTR;            // 65,536
    float* wsel    = probs + (size_t)NN * EE;              // 65,536
    float* partial = wsel + (size_t)NN * EE;               // 65,536
    float* mean_x  = partial + (size_t)BB * NCH * DD;      // 4,096
    float* gctx    = mean_x + (size_t)BB * DD;             // 512
    float* rqv     = gctx + (size_t)BB * DLb;              // 512
    unsigned short* abf  = (unsigned short*)(rqv + (size_t)BB * DLb);   // NN*1024 ushorts
    unsigned short* wupT = abf + (size_t)NN * DD;                       // 1024*1024 ushorts

    hipLaunchKernelGGL(k1a, dim3(DD / 256, BB, NCH), dim3(256), 0, stream, x, partial);
    hipLaunchKernelGGL(k1b, dim3(DD / 256, BB), dim3(256), 0, stream, partial, mean_x);
    hipLaunchKernelGGL(k2_batch, dim3(BB), dim3(DLb), 0, stream,
                       mean_x, gpw, gpb, rq1w, rq1b, rqlnw, rqlnb, rq2w, rq2b, gctx, rqv);
    hipLaunchKernelGGL(k2b, dim3(NN * DLb / 256), dim3(256), 0, stream, gctx, seq);
    hipLaunchKernelGGL(k3_gemm, dim3((EE * DLb) / 128, NN / 128), dim3(256), 0, stream, x, wdown, pe, seq);
    hipLaunchKernelGGL(k4_token, dim3(NN), dim3(256), 0, stream,
                       seq, aiw, aib, aow, aob, nw, nb, rkw, rkb, rqv, probs, wsel);
    hipLaunchKernelGGL(k5t, dim3(DD / 64, DD / 64), dim3(256), 0, stream, wup, wupT);
    hipLaunchKernelGGL(k5pre, dim3(NN * DD / (256 * 8)), dim3(256), 0, stream, seq, pe, wsel, abf);
    hipLaunchKernelGGL(k5_mfma, dim3(DD / 128, NN / 128), dim3(256), 0, stream, abf, wupT, out);
    hipLaunchKernelGGL(k6_aux, dim3(1), dim3(256), 0, stream, probs, wsel, out + (size_t)NN * DD);
}

// Round 3
// 645.169 us; speedup vs baseline: 1.6419x; 1.6326x over previous
//
#include <hip/hip_runtime.h>
#include <hip/hip_bf16.h>
#include <math.h>

#define BB 4
#define TT 2048
#define DD 1024
#define DLb 128
#define EE 8
#define HH 4
#define KK 3
#define HDh 32
#define NN (BB*TT)
#define NPOS 9
#define NCH 16
#define CHL (TT/NCH)
#define SEQSTR (NPOS*DLb)   // 1152
#define NSLICE 4
#define TSL (NN/NSLICE)     // 2048 tokens per slice

typedef __attribute__((ext_vector_type(8))) short short8;
typedef __attribute__((ext_vector_type(4))) float f32x4;
typedef __attribute__((ext_vector_type(8))) unsigned short ushort8;

__device__ __forceinline__ float gelu_exact(float v) {
    return 0.5f * v * (1.0f + erff(v * 0.70710678118654752440f));
}

__device__ __forceinline__ unsigned short f2bf(float x) {
    __hip_bfloat16 h = __float2bfloat16(x);
    return *reinterpret_cast<unsigned short*>(&h);
}

// ---------------- K1: per-batch column mean of x ----------------
__global__ __launch_bounds__(256) void k1a(const float* __restrict__ x, float* __restrict__ partial) {
    int d = blockIdx.x * 256 + threadIdx.x;
    int b = blockIdx.y, c = blockIdx.z;
    const float* xp = x + ((size_t)b * TT + (size_t)c * CHL) * DD + d;
    float s = 0.0f;
    for (int t = 0; t < CHL; t++) s += xp[(size_t)t * DD];
    partial[(b * NCH + c) * DD + d] = s;
}

__global__ __launch_bounds__(256) void k1b(const float* __restrict__ partial, float* __restrict__ mean_x) {
    int d = blockIdx.x * 256 + threadIdx.x;
    int b = blockIdx.y;
    float s = 0.0f;
    for (int c = 0; c < NCH; c++) s += partial[(b * NCH + c) * DD + d];
    mean_x[b * DD + d] = s * (1.0f / TT);
}

// ---------------- K2: per-batch gctx + rq chain ----------------
__global__ __launch_bounds__(128) void k2_batch(
    const float* __restrict__ mean_x,
    const float* __restrict__ gpw, const float* __restrict__ gpb,
    const float* __restrict__ rq1w, const float* __restrict__ rq1b,
    const float* __restrict__ lnw, const float* __restrict__ lnb,
    const float* __restrict__ rq2w, const float* __restrict__ rq2b,
    float* __restrict__ gctx, float* __restrict__ rqv)
{
    int b = blockIdx.x, d = threadIdx.x;
    __shared__ __attribute__((aligned(16))) float g[DLb];
    __shared__ __attribute__((aligned(16))) float t1[DLb];
    __shared__ __attribute__((aligned(16))) float act[DLb];
    __shared__ float red[2];
    {
        const float4* wrow = (const float4*)(gpw + (size_t)d * DD);
        const float4* mx4  = (const float4*)(mean_x + (size_t)b * DD);
        float s = gpb[d];
        for (int k = 0; k < DD / 4; k++) {
            float4 w = wrow[k], m = mx4[k];
            s += w.x * m.x + w.y * m.y + w.z * m.z + w.w * m.w;
        }
        g[d] = s;
        gctx[b * DLb + d] = s;
    }
    __syncthreads();
    {
        float s = rq1b[d];
        for (int k = 0; k < DLb; k++) s += g[k] * rq1w[d * DLb + k];
        t1[d] = s;
    }
    __syncthreads();
    if (d == 0) {
        float m = 0.0f;
        for (int i = 0; i < DLb; i++) m += t1[i];
        m *= (1.0f / DLb);
        float v = 0.0f;
        for (int i = 0; i < DLb; i++) { float df = t1[i] - m; v += df * df; }
        v *= (1.0f / DLb);
        red[0] = m; red[1] = 1.0f / sqrtf(v + 1e-5f);
    }
    __syncthreads();
    {
        float xn = (t1[d] - red[0]) * red[1] * lnw[d] + lnb[d];
        act[d] = gelu_exact(xn);
    }
    __syncthreads();
    {
        float s = rq2b[d];
        for (int k = 0; k < DLb; k++) s += act[k] * rq2w[d * DLb + k];
        rqv[b * DLb + d] = s;
    }
}

// ---------------- K2b: fill seq position 0 with gctx ----------------
__global__ __launch_bounds__(256) void k2b(const float* __restrict__ gctx, float* __restrict__ seq) {
    int i = blockIdx.x * 256 + threadIdx.x;   // over NN*DLb
    int n = i >> 7, d = i & 127;
    seq[(size_t)n * SEQSTR + d] = gctx[(n >> 11) * DLb + d];
}

// ---------------- K3: seq[:,1:,:] = x @ w_down^T + pe (fp32 128x128 tile) ----------------
__global__ __launch_bounds__(256) void k3_gemm(const float* __restrict__ A,
                                               const float* __restrict__ W,
                                               const float* __restrict__ pe,
                                               float* __restrict__ seq)
{
    __shared__ __attribute__((aligned(16))) float As[16][132];
    __shared__ __attribute__((aligned(16))) float Bs[16][132];
    int tid = threadIdx.x;
    int tx = tid & 15, ty = tid >> 4;
    int row0 = blockIdx.y * 128, col0 = blockIdx.x * 128;
    float acc[8][8] = {};
    for (int k0 = 0; k0 < DD; k0 += 16) {
        #pragma unroll
        for (int i = 0; i < 2; i++) {
            int L = i * 256 + tid;
            int r = L >> 2, kq = (L & 3) * 4;
            float4 a4 = *(const float4*)&A[(size_t)(row0 + r) * DD + k0 + kq];
            float4 b4 = *(const float4*)&W[(size_t)(col0 + r) * DD + k0 + kq];
            As[kq + 0][r] = a4.x; As[kq + 1][r] = a4.y; As[kq + 2][r] = a4.z; As[kq + 3][r] = a4.w;
            Bs[kq + 0][r] = b4.x; Bs[kq + 1][r] = b4.y; Bs[kq + 2][r] = b4.z; Bs[kq + 3][r] = b4.w;
        }
        __syncthreads();
        #pragma unroll
        for (int kk = 0; kk < 16; kk++) {
            float4 a0 = *(const float4*)&As[kk][ty * 4];
            float4 a1 = *(const float4*)&As[kk][64 + ty * 4];
            float4 b0 = *(const float4*)&Bs[kk][tx * 4];
            float4 b1 = *(const float4*)&Bs[kk][64 + tx * 4];
            float ar[8] = {a0.x, a0.y, a0.z, a0.w, a1.x, a1.y, a1.z, a1.w};
            float bc[8] = {b0.x, b0.y, b0.z, b0.w, b1.x, b1.y, b1.z, b1.w};
            #pragma unroll
            for (int i = 0; i < 8; i++)
                #pragma unroll
                for (int j = 0; j < 8; j++)
                    acc[i][j] += ar[i] * bc[j];
        }
        __syncthreads();
    }
    float4 pe0 = *(const float4*)&pe[col0 + tx * 4];
    float4 pe1 = *(const float4*)&pe[col0 + 64 + tx * 4];
    #pragma unroll
    for (int i = 0; i < 8; i++) {
        int gr = row0 + ((i < 4) ? (ty * 4 + i) : (64 + ty * 4 + (i - 4)));
        float* dst = seq + (size_t)gr * SEQSTR + DLb + col0;
        float4 o0; o0.x = acc[i][0] + pe0.x; o0.y = acc[i][1] + pe0.y; o0.z = acc[i][2] + pe0.z; o0.w = acc[i][3] + pe0.w;
        float4 o1; o1.x = acc[i][4] + pe1.x; o1.y = acc[i][5] + pe1.y; o1.z = acc[i][6] + pe1.z; o1.w = acc[i][7] + pe1.w;
        *(float4*)&dst[tx * 4] = o0;
        *(float4*)&dst[64 + tx * 4] = o1;
    }
}

// ---------------- K4a: qkv slice GEMM: C = A @ W^T + bias ----------------
// A: (TSL*9, 128) slice of seq; W: (384,128); C: (TSL*9, 384)
__global__ __launch_bounds__(256) void k4a(const float* __restrict__ A,
                                           const float* __restrict__ W,
                                           const float* __restrict__ bias,
                                           float* __restrict__ C)
{
    __shared__ __attribute__((aligned(16))) float As[16][132];
    __shared__ __attribute__((aligned(16))) float Bs[16][132];
    int tid = threadIdx.x;
    int tx = tid & 15, ty = tid >> 4;
    int row0 = blockIdx.y * 128, col0 = blockIdx.x * 128;
    float acc[8][8] = {};
    for (int k0 = 0; k0 < DLb; k0 += 16) {
        #pragma unroll
        for (int i = 0; i < 2; i++) {
            int L = i * 256 + tid;
            int r = L >> 2, kq = (L & 3) * 4;
            float4 a4 = *(const float4*)&A[(size_t)(row0 + r) * DLb + k0 + kq];
            float4 b4 = *(const float4*)&W[(size_t)(col0 + r) * DLb + k0 + kq];
            As[kq + 0][r] = a4.x; As[kq + 1][r] = a4.y; As[kq + 2][r] = a4.z; As[kq + 3][r] = a4.w;
            Bs[kq + 0][r] = b4.x; Bs[kq + 1][r] = b4.y; Bs[kq + 2][r] = b4.z; Bs[kq + 3][r] = b4.w;
        }
        __syncthreads();
        #pragma unroll
        for (int kk = 0; kk < 16; kk++) {
            float4 a0 = *(const float4*)&As[kk][ty * 4];
            float4 a1 = *(const float4*)&As[kk][64 + ty * 4];
            float4 b0 = *(const float4*)&Bs[kk][tx * 4];
            float4 b1 = *(const float4*)&Bs[kk][64 + tx * 4];
            float ar[8] = {a0.x, a0.y, a0.z, a0.w, a1.x, a1.y, a1.z, a1.w};
            float bc[8] = {b0.x, b0.y, b0.z, b0.w, b1.x, b1.y, b1.z, b1.w};
            #pragma unroll
            for (int i = 0; i < 8; i++)
                #pragma unroll
                for (int j = 0; j < 8; j++)
                    acc[i][j] += ar[i] * bc[j];
        }
        __syncthreads();
    }
    float4 bb0 = *(const float4*)&bias[col0 + tx * 4];
    float4 bb1 = *(const float4*)&bias[col0 + 64 + tx * 4];
    #pragma unroll
    for (int i = 0; i < 8; i++) {
        int gr = row0 + ((i < 4) ? (ty * 4 + i) : (64 + ty * 4 + (i - 4)));
        float* dst = C + (size_t)gr * 384 + col0;
        float4 o0; o0.x = acc[i][0] + bb0.x; o0.y = acc[i][1] + bb0.y; o0.z = acc[i][2] + bb0.z; o0.w = acc[i][3] + bb0.w;
        float4 o1; o1.x = acc[i][4] + bb1.x; o1.y = acc[i][5] + bb1.y; o1.z = acc[i][6] + bb1.z; o1.w = acc[i][7] + bb1.w;
        *(float4*)&dst[tx * 4] = o0;
        *(float4*)&dst[64 + tx * 4] = o1;
    }
}

// ---------------- K4b: per-token attention (softmax + attn@v), pos 1..8 only ----------------
__global__ __launch_bounds__(256) void k4b(const float* __restrict__ qkv,
                                           float* __restrict__ og, int n0)
{
    int nl = blockIdx.x;
    int tid = threadIdx.x;
    __shared__ __attribute__((aligned(16))) float sq[NPOS][384];
    __shared__ float attnw[HH][NPOS][12];
    {
        const float4* src = (const float4*)(qkv + (size_t)nl * NPOS * 384);
        float4* dst = (float4*)&sq[0][0];
        for (int i = tid; i < NPOS * 384 / 4; i += 256) dst[i] = src[i];
    }
    __syncthreads();
    if (tid < HH * NPOS) {
        int h = tid / NPOS, i = tid % NPOS;
        float sc[NPOS];
        float mx = -1e30f;
        for (int j = 0; j < NPOS; j++) {
            float s = 0.0f;
            for (int d2 = 0; d2 < HDh; d2++)
                s += sq[i][h * HDh + d2] * sq[j][DLb + h * HDh + d2];
            s *= 0.17677669529663687f;  // 1/sqrt(32)
            sc[j] = s;
            mx = fmaxf(mx, s);
        }
        float se = 0.0f;
        for (int j = 0; j < NPOS; j++) { sc[j] = expf(sc[j] - mx); se += sc[j]; }
        float inv = 1.0f / se;
        for (int j = 0; j < NPOS; j++) attnw[h][i][j] = sc[j] * inv;
    }
    __syncthreads();
    #pragma unroll
    for (int it = 0; it < 4; it++) {
        int idx = it * 256 + tid;          // 0..1023 -> (p-1, d)
        int p = 1 + (idx >> 7), d = idx & 127, h = d >> 5;
        float s = 0.0f;
        #pragma unroll
        for (int j = 0; j < NPOS; j++) s += attnw[h][p][j] * sq[j][2 * DLb + d];
        og[((size_t)(n0 + nl) * 8 + (p - 1)) * DLb + d] = s;
    }
}

// ---------------- K4c: s2 = LN(o @ aow^T + aob + residual) (M=65536, N=K=128) ----------------
__global__ __launch_bounds__(256) void k4c(const float* __restrict__ A,
                                           const float* __restrict__ W,
                                           const float* __restrict__ bias,
                                           const float* __restrict__ seq,
                                           const float* __restrict__ nw,
                                           const float* __restrict__ nb,
                                           float* __restrict__ s2)
{
    __shared__ __attribute__((aligned(16))) float As[16][132];
    __shared__ __attribute__((aligned(16))) float Bs[16][132];
    __shared__ float redS[128][17];
    __shared__ float mstat[128][2];
    int tid = threadIdx.x;
    int tx = tid & 15, ty = tid >> 4;
    int row0 = blockIdx.y * 128;
    float acc[8][8] = {};
    for (int k0 = 0; k0 < DLb; k0 += 16) {
        #pragma unroll
        for (int i = 0; i < 2; i++) {
            int L = i * 256 + tid;
            int r = L >> 2, kq = (L & 3) * 4;
            float4 a4 = *(const float4*)&A[(size_t)(row0 + r) * DLb + k0 + kq];
            float4 b4 = *(const float4*)&W[(size_t)r * DLb + k0 + kq];
            As[kq + 0][r] = a4.x; As[kq + 1][r] = a4.y; As[kq + 2][r] = a4.z; As[kq + 3][r] = a4.w;
            Bs[kq + 0][r] = b4.x; Bs[kq + 1][r] = b4.y; Bs[kq + 2][r] = b4.z; Bs[kq + 3][r] = b4.w;
        }
        __syncthreads();
        #pragma unroll
        for (int kk = 0; kk < 16; kk++) {
            float4 a0 = *(const float4*)&As[kk][ty * 4];
            float4 a1 = *(const float4*)&As[kk][64 + ty * 4];
            float4 b0 = *(const float4*)&Bs[kk][tx * 4];
            float4 b1 = *(const float4*)&Bs[kk][64 + tx * 4];
            float ar[8] = {a0.x, a0.y, a0.z, a0.w, a1.x, a1.y, a1.z, a1.w};
            float bc[8] = {b0.x, b0.y, b0.z, b0.w, b1.x, b1.y, b1.z, b1.w};
            #pragma unroll
            for (int i = 0; i < 8; i++)
                #pragma unroll
                for (int j = 0; j < 8; j++)
                    acc[i][j] += ar[i] * bc[j];
        }
        __syncthreads();
    }
    float4 bb0 = *(const float4*)&bias[tx * 4];
    float4 bb1 = *(const float4*)&bias[64 + tx * 4];
    // add bias + residual in place; partial row-sums
    #pragma unroll
    for (int i = 0; i < 8; i++) {
        int rl = (i < 4) ? (ty * 4 + i) : (64 + ty * 4 + (i - 4));
        int m = row0 + rl;
        const float* res = seq + (size_t)(m >> 3) * SEQSTR + (size_t)((m & 7) + 1) * DLb;
        float4 r0 = *(const float4*)&res[tx * 4];
        float4 r1 = *(const float4*)&res[64 + tx * 4];
        acc[i][0] += bb0.x + r0.x; acc[i][1] += bb0.y + r0.y;
        acc[i][2] += bb0.z + r0.z; acc[i][3] += bb0.w + r0.w;
        acc[i][4] += bb1.x + r1.x; acc[i][5] += bb1.y + r1.y;
        acc[i][6] += bb1.z + r1.z; acc[i][7] += bb1.w + r1.w;
        float ps = 0.0f;
        #pragma unroll
        for (int j = 0; j < 8; j++) ps += acc[i][j];
        redS[rl][tx] = ps;
    }
    __syncthreads();
    if (tid < 128) {
        float s = 0.0f;
        #pragma unroll
        for (int t = 0; t < 16; t++) s += redS[tid][t];
        mstat[tid][0] = s * (1.0f / DLb);
    }
    __syncthreads();
    #pragma unroll
    for (int i = 0; i < 8; i++) {
        int rl = (i < 4) ? (ty * 4 + i) : (64 + ty * 4 + (i - 4));
        float m = mstat[rl][0];
        float pv = 0.0f;
        #pragma unroll
        for (int j = 0; j < 8; j++) { float df = acc[i][j] - m; pv += df * df; }
        redS[rl][tx] = pv;
    }
    __syncthreads();
    if (tid < 128) {
        float s = 0.0f;
        #pragma unroll
        for (int t = 0; t < 16; t++) s += redS[tid][t];
        mstat[tid][1] = 1.0f / sqrtf(s * (1.0f / DLb) + 1e-5f);
    }
    __syncthreads();
    float4 nw0 = *(const float4*)&nw[tx * 4];
    float4 nw1 = *(const float4*)&nw[64 + tx * 4];
    float4 nb0 = *(const float4*)&nb[tx * 4];
    float4 nb1 = *(const float4*)&nb[64 + tx * 4];
    #pragma unroll
    for (int i = 0; i < 8; i++) {
        int rl = (i < 4) ? (ty * 4 + i) : (64 + ty * 4 + (i - 4));
        float m = mstat[rl][0], istd = mstat[rl][1];
        float* dst = s2 + (size_t)(row0 + rl) * DLb;
        float4 o0, o1;
        o0.x = (acc[i][0] - m) * istd * nw0.x + nb0.x;
        o0.y = (acc[i][1] - m) * istd * nw0.y + nb0.y;
        o0.z = (acc[i][2] - m) * istd * nw0.z + nb0.z;
        o0.w = (acc[i][3] - m) * istd * nw0.w + nb0.w;
        o1.x = (acc[i][4] - m) * istd * nw1.x + nb1.x;
        o1.y = (acc[i][5] - m) * istd * nw1.y + nb1.y;
        o1.z = (acc[i][6] - m) * istd * nw1.z + nb1.z;
        o1.w = (acc[i][7] - m) * istd * nw1.w + nb1.w;
        *(float4*)&dst[tx * 4] = o0;
        *(float4*)&dst[64 + tx * 4] = o1;
    }
}

// ---------------- K4d: rk GEMM + fused logits (no rk materialization) ----------------
__global__ __launch_bounds__(256) void k4d(const float* __restrict__ A,
                                           const float* __restrict__ W,
                                           const float* __restrict__ bias,
                                           const float* __restrict__ rqv,
                                           float* __restrict__ logits)
{
    __shared__ __attribute__((aligned(16))) float As[16][132];
    __shared__ __attribute__((aligned(16))) float Bs[16][132];
    __shared__ float redS[128][17];
    int tid = threadIdx.x;
    int tx = tid & 15, ty = tid >> 4;
    int row0 = blockIdx.y * 128;
    float acc[8][8] = {};
    for (int k0 = 0; k0 < DLb; k0 += 16) {
        #pragma unroll
        for (int i = 0; i < 2; i++) {
            int L = i * 256 + tid;
            int r = L >> 2, kq = (L & 3) * 4;
            float4 a4 = *(const float4*)&A[(size_t)(row0 + r) * DLb + k0 + kq];
            float4 b4 = *(const float4*)&W[(size_t)r * DLb + k0 + kq];
            As[kq + 0][r] = a4.x; As[kq + 1][r] = a4.y; As[kq + 2][r] = a4.z; As[kq + 3][r] = a4.w;
            Bs[kq + 0][r] = b4.x; Bs[kq + 1][r] = b4.y; Bs[kq + 2][r] = b4.z; Bs[kq + 3][r] = b4.w;
        }
        __syncthreads();
        #pragma unroll
        for (int kk = 0; kk < 16; kk++) {
            float4 a0 = *(const float4*)&As[kk][ty * 4];
            float4 a1 = *(const float4*)&As[kk][64 + ty * 4];
            float4 b0 = *(const float4*)&Bs[kk][tx * 4];
            float4 b1 = *(const float4*)&Bs[kk][64 + tx * 4];
            float ar[8] = {a0.x, a0.y, a0.z, a0.w, a1.x, a1.y, a1.z, a1.w};
            float bc[8] = {b0.x, b0.y, b0.z, b0.w, b1.x, b1.y, b1.z, b1.w};
            #pragma unroll
            for (int i = 0; i < 8; i++)
                #pragma unroll
                for (int j = 0; j < 8; j++)
                    acc[i][j] += ar[i] * bc[j];
        }
        __syncthreads();
    }
    int b = row0 >> 14;   // 16384 rows per batch; 128 | 16384 so uniform per block
    const float* rq = rqv + b * DLb;
    float4 bb0 = *(const float4*)&bias[tx * 4];
    float4 bb1 = *(const float4*)&bias[64 + tx * 4];
    float4 q0 = *(const float4*)&rq[tx * 4];
    float4 q1 = *(const float4*)&rq[64 + tx * 4];
    #pragma unroll
    for (int i = 0; i < 8; i++) {
        int rl = (i < 4) ? (ty * 4 + i) : (64 + ty * 4 + (i - 4));
        float ps = (acc[i][0] + bb0.x) * q0.x + (acc[i][1] + bb0.y) * q0.y
                 + (acc[i][2] + bb0.z) * q0.z + (acc[i][3] + bb0.w) * q0.w
                 + (acc[i][4] + bb1.x) * q1.x + (acc[i][5] + bb1.y) * q1.y
                 + (acc[i][6] + bb1.z) * q1.z + (acc[i][7] + bb1.w) * q1.w;
        redS[rl][tx] = ps;
    }
    __syncthreads();
    if (tid < 128) {
        float s = 0.0f;
        #pragma unroll
        for (int t = 0; t < 16; t++) s += redS[tid][t];
        logits[row0 + tid] = s * 0.08838834764831845f;   // 1/sqrt(128)
    }
}

// ---------------- K4e: per-token softmax + top-3 + wsel ----------------
__global__ __launch_bounds__(256) void k4e(const float* __restrict__ logits,
                                           float* __restrict__ probs,
                                           float* __restrict__ wsel)
{
    int n = blockIdx.x * 256 + threadIdx.x;
    if (n >= NN) return;
    float lg[EE];
    float4 l0 = *(const float4*)&logits[(size_t)n * EE];
    float4 l1 = *(const float4*)&logits[(size_t)n * EE + 4];
    lg[0] = l0.x; lg[1] = l0.y; lg[2] = l0.z; lg[3] = l0.w;
    lg[4] = l1.x; lg[5] = l1.y; lg[6] = l1.z; lg[7] = l1.w;
    float mx = lg[0];
    #pragma unroll
    for (int e = 1; e < EE; e++) mx = fmaxf(mx, lg[e]);
    float pr[EE];
    float se = 0.0f;
    #pragma unroll
    for (int e = 0; e < EE; e++) { pr[e] = expf(lg[e] - mx); se += pr[e]; }
    float inv = 1.0f / se;
    #pragma unroll
    for (int e = 0; e < EE; e++) pr[e] *= inv;
    float4 p0, p1;
    p0.x = pr[0]; p0.y = pr[1]; p0.z = pr[2]; p0.w = pr[3];
    p1.x = pr[4]; p1.y = pr[5]; p1.z = pr[6]; p1.w = pr[7];
    *(float4*)&probs[(size_t)n * EE] = p0;
    *(float4*)&probs[(size_t)n * EE + 4] = p1;
    bool used[EE] = {};
    int sel[KK];
    float sw = 0.0f;
    for (int t = 0; t < KK; t++) {
        int bi = 0; float bv = -1e30f;
        for (int e = 0; e < EE; e++)
            if (!used[e] && pr[e] > bv) { bv = pr[e]; bi = e; }
        used[bi] = true; sel[t] = bi; sw += pr[bi];
    }
    float invsw = 1.0f / sw;
    float w8[EE];
    #pragma unroll
    for (int e = 0; e < EE; e++) w8[e] = 0.0f;
    for (int t = 0; t < KK; t++) w8[sel[t]] = pr[sel[t]] * invsw;
    float4 w0, w1;
    w0.x = w8[0]; w0.y = w8[1]; w0.z = w8[2]; w0.w = w8[3];
    w1.x = w8[4]; w1.y = w8[5]; w1.z = w8[6]; w1.w = w8[7];
    *(float4*)&wsel[(size_t)n * EE] = w0;
    *(float4*)&wsel[(size_t)n * EE + 4] = w1;
}

// ---------------- K5pre: a_bf16[n][k] = wsel[n][k>>7] * gelu(seq - pe) ----------------
__global__ __launch_bounds__(256) void k5pre(const float* __restrict__ seq,
                                             const float* __restrict__ pe,
                                             const float* __restrict__ wsel,
                                             unsigned short* __restrict__ abf)
{
    size_t g = ((size_t)blockIdx.x * 256 + threadIdx.x) * 8;
    int n = (int)(g >> 10), k0 = (int)(g & 1023);
    int e = k0 >> 7;
    float w = wsel[(size_t)n * EE + e];
    const float* sp = seq + (size_t)n * SEQSTR + DLb + k0;
    float4 s0 = *(const float4*)&sp[0];
    float4 s1 = *(const float4*)&sp[4];
    float4 p0 = *(const float4*)&pe[k0];
    float4 p1 = *(const float4*)&pe[k0 + 4];
    float v[8];
    v[0] = w * gelu_exact(s0.x - p0.x); v[1] = w * gelu_exact(s0.y - p0.y);
    v[2] = w * gelu_exact(s0.z - p0.z); v[3] = w * gelu_exact(s0.w - p0.w);
    v[4] = w * gelu_exact(s1.x - p1.x); v[5] = w * gelu_exact(s1.y - p1.y);
    v[6] = w * gelu_exact(s1.z - p1.z); v[7] = w * gelu_exact(s1.w - p1.w);
    ushort8 o;
    #pragma unroll
    for (int i = 0; i < 8; i++) o[i] = f2bf(v[i]);
    *(ushort8*)&abf[g] = o;
}

// ---------------- K5t: wupT[m][k] = bf16(wup[k][m]) ----------------
__global__ __launch_bounds__(256) void k5t(const float* __restrict__ wup, unsigned short* __restrict__ wupT) {
    __shared__ float T[64][68];
    int tid = threadIdx.x;
    int k0 = blockIdx.x * 64, m0 = blockIdx.y * 64;
    #pragma unroll
    for (int i = 0; i < 4; i++) {
        int F = i * 256 + tid;
        int r = F >> 4, c4 = (F & 15) * 4;
        *(float4*)&T[r][c4] = *(const float4*)&wup[(size_t)(k0 + r) * DD + m0 + c4];
    }
    __syncthreads();
    #pragma unroll
    for (int i = 0; i < 2; i++) {
        int W = i * 256 + tid;
        int r = W >> 3, c8 = (W & 7) * 8;
        ushort8 o;
        #pragma unroll
        for (int j = 0; j < 8; j++) o[j] = f2bf(T[c8 + j][r]);
        *(ushort8*)&wupT[(size_t)(m0 + r) * DD + k0 + c8] = o;
    }
}

// ---------------- K5: out = a_bf16 @ wupT^T via MFMA 16x16x32 bf16 ----------------
#define RSA 40
__global__ __launch_bounds__(256) void k5_mfma(const unsigned short* __restrict__ A,
                                               const unsigned short* __restrict__ B,
                                               float* __restrict__ C)
{
    __shared__ __attribute__((aligned(16))) unsigned short As[128 * RSA];
    __shared__ __attribute__((aligned(16))) unsigned short Bs[128 * RSA];
    int tid = threadIdx.x;
    int lane = tid & 63, wave = tid >> 6;
    int wm = wave & 1, wn = wave >> 1;
    int row0 = blockIdx.y * 128, col0 = blockIdx.x * 128;
    int fr = lane & 15, fq = lane >> 4;
    f32x4 acc[4][4];
    #pragma unroll
    for (int i = 0; i < 4; i++)
        #pragma unroll
        for (int j = 0; j < 4; j++) acc[i][j] = (f32x4)0.0f;

    for (int k0 = 0; k0 < DD; k0 += 32) {
        #pragma unroll
        for (int i = 0; i < 2; i++) {
            int L = i * 256 + tid;
            int r = L >> 2, q = (L & 3) * 8;
            *(ushort8*)&As[r * RSA + q] = *(const ushort8*)&A[(size_t)(row0 + r) * DD + k0 + q];
            *(ushort8*)&Bs[r * RSA + q] = *(const ushort8*)&B[(size_t)(col0 + r) * DD + k0 + q];
        }
        __syncthreads();
        short8 af[4], bf[4];
        #pragma unroll
        for (int f = 0; f < 4; f++) {
            af[f] = *(const short8*)&As[(wm * 64 + f * 16 + fr) * RSA + fq * 8];
            bf[f] = *(const short8*)&Bs[(wn * 64 + f * 16 + fr) * RSA + fq * 8];
        }
        #pragma unroll
        for (int i = 0; i < 4; i++)
            #pragma unroll
            for (int j = 0; j < 4; j++)
                acc[i][j] = __builtin_amdgcn_mfma_f32_16x16x32_bf16(af[i], bf[j], acc[i][j], 0, 0, 0);
        __syncthreads();
    }
    #pragma unroll
    for (int i = 0; i < 4; i++) {
        #pragma unroll
        for (int j = 0; j < 4; j++) {
            int gc = col0 + wn * 64 + j * 16 + fr;
            #pragma unroll
            for (int r = 0; r < 4; r++) {
                int gr = row0 + wm * 64 + i * 16 + fq * 4 + r;
                C[(size_t)gr * DD + gc] = acc[i][j][r];
            }
        }
    }
}

// ---------------- K6: aux loss ----------------
__global__ __launch_bounds__(256) void k6_aux(const float* __restrict__ probs,
                                              const float* __restrict__ wsel,
                                              float* __restrict__ out_aux)
{
    int tid = threadIdx.x;
    float lp[EE], lc[EE];
    #pragma unroll
    for (int e = 0; e < EE; e++) { lp[e] = 0.0f; lc[e] = 0.0f; }
    for (int n = tid; n < NN; n += 256) {
        #pragma unroll
        for (int e = 0; e < EE; e++) {
            lp[e] += probs[(size_t)n * EE + e];
            lc[e] += (wsel[(size_t)n * EE + e] > 0.0f) ? 1.0f : 0.0f;
        }
    }
    __shared__ float bp[256][EE];
    __shared__ float bc[256][EE];
    #pragma unroll
    for (int e = 0; e < EE; e++) { bp[tid][e] = lp[e]; bc[tid][e] = lc[e]; }
    __syncthreads();
    for (int s = 128; s > 0; s >>= 1) {
        if (tid < s) {
            #pragma unroll
            for (int e = 0; e < EE; e++) {
                bp[tid][e] += bp[tid + s][e];
                bc[tid][e] += bc[tid + s][e];
            }
        }
        __syncthreads();
    }
    if (tid == 0) {
        float a = 0.0f;
        for (int e = 0; e < EE; e++) a += (bp[0][e] / NN) * (bc[0][e] / NN);
        out_aux[0] = EE * a;
    }
}

extern "C" void kernel_launch(void* const* d_in, const int* in_sizes, int n_in,
                              void* d_out, int out_size, void* d_ws, size_t ws_size,
                              hipStream_t stream) {
    const float* x     = (const float*)d_in[0];
    const float* wdown = (const float*)d_in[1];
    const float* pe    = (const float*)d_in[2];
    const float* gpw   = (const float*)d_in[3];
    const float* gpb   = (const float*)d_in[4];
    const float* aiw   = (const float*)d_in[5];
    const float* aib   = (const float*)d_in[6];
    const float* aow   = (const float*)d_in[7];
    const float* aob   = (const float*)d_in[8];
    const float* nw    = (const float*)d_in[9];
    const float* nb    = (const float*)d_in[10];
    const float* rq1w  = (const float*)d_in[11];
    const float* rq1b  = (const float*)d_in[12];
    const float* rqlnw = (const float*)d_in[13];
    const float* rqlnb = (const float*)d_in[14];
    const float* rq2w  = (const float*)d_in[15];
    const float* rq2b  = (const float*)d_in[16];
    const float* rkw   = (const float*)d_in[17];
    const float* rkb   = (const float*)d_in[18];
    const float* wup   = (const float*)d_in[19];

    float* out = (float*)d_out;

    float* seq    = (float*)d_ws;                      // NN*1152        = 9,437,184 f
    float* o      = seq + (size_t)NN * SEQSTR;         // 65536*128      = 8,388,608 f
    float* region = o + (size_t)NN * EE * DLb / 8 * 8; // qkv slices / s2: 8,388,608 f
    float* qkvbuf = region;                            // 18432*384 = 7,077,888 <= 8,388,608
    float* s2     = region;                            // aliases qkv (qkv dead before k4c)
    float* probs  = region + (size_t)65536 * 128;
    float* wsel   = probs + (size_t)NN * EE;
    float* logits = wsel + (size_t)NN * EE;
    float* partial= logits + (size_t)NN * EE;
    float* mean_x = partial + (size_t)BB * NCH * DD;
    float* gctx   = mean_x + (size_t)BB * DD;
    float* rqv    = gctx + (size_t)BB * DLb;
    unsigned short* wupT = (unsigned short*)(rqv + (size_t)BB * DLb);   // 1,048,576 us
    unsigned short* abf  = (unsigned short*)o;         // aliases o (dead after k4c)

    hipLaunchKernelGGL(k1a, dim3(DD / 256, BB, NCH), dim3(256), 0, stream, x, partial);
    hipLaunchKernelGGL(k1b, dim3(DD / 256, BB), dim3(256), 0, stream, partial, mean_x);
    hipLaunchKernelGGL(k2_batch, dim3(BB), dim3(DLb), 0, stream,
                       mean_x, gpw, gpb, rq1w, rq1b, rqlnw, rqlnb, rq2w, rq2b, gctx, rqv);
    hipLaunchKernelGGL(k2b, dim3(NN * DLb / 256), dim3(256), 0, stream, gctx, seq);
    hipLaunchKernelGGL(k3_gemm, dim3((EE * DLb) / 128, NN / 128), dim3(256), 0, stream, x, wdown, pe, seq);
    for (int s = 0; s < NSLICE; s++) {
        hipLaunchKernelGGL(k4a, dim3(3, TSL * NPOS / 128), dim3(256), 0, stream,
                           seq + (size_t)s * TSL * SEQSTR, aiw, aib, qkvbuf);
        hipLaunchKernelGGL(k4b, dim3(TSL), dim3(256), 0, stream, qkvbuf, o, s * TSL);
    }
    hipLaunchKernelGGL(k4c, dim3(1, NN * EE / 128), dim3(256), 0, stream,
                       o, aow, aob, seq, nw, nb, s2);
    hipLaunchKernelGGL(k4d, dim3(1, NN * EE / 128), dim3(256), 0, stream,
                       s2, rkw, rkb, rqv, logits);
    hipLaunchKernelGGL(k4e, dim3(NN / 256), dim3(256), 0, stream, logits, probs, wsel);
    hipLaunchKernelGGL(k5t, dim3(DD / 64, DD / 64), dim3(256), 0, stream, wup, wupT);
    hipLaunchKernelGGL(k5pre, dim3(NN * DD / (256 * 8)), dim3(256), 0, stream, seq, pe, wsel, abf);
    hipLaunchKernelGGL(k5_mfma, dim3(DD / 128, NN / 128), dim3(256), 0, stream, abf, wupT, out);
    hipLaunchKernelGGL(k6_aux, dim3(1), dim3(256), 0, stream, probs, wsel, out + (size_t)NN * DD);
}

// Round 4
// 435.721 us; speedup vs baseline: 2.4312x; 1.4807x over previous
//
#include <hip/hip_runtime.h>
#include <hip/hip_bf16.h>
#include <math.h>

#define BB 4
#define TT 2048
#define DD 1024
#define DLb 128
#define EE 8
#define HH 4
#define KK 3
#define HDh 32
#define NN (BB*TT)
#define NPOS 9
#define NCH 16
#define CHL (TT/NCH)
#define SEQSTR (NPOS*DLb)   // 1152
#define NSLICE 4
#define TSL (NN/NSLICE)     // 2048 tokens per slice

typedef __attribute__((ext_vector_type(8))) short short8;
typedef __attribute__((ext_vector_type(4))) float f32x4;
typedef __attribute__((ext_vector_type(8))) unsigned short ushort8;

__device__ __forceinline__ float gelu_exact(float v) {
    return 0.5f * v * (1.0f + erff(v * 0.70710678118654752440f));
}

__device__ __forceinline__ unsigned short f2bf(float x) {
    __hip_bfloat16 h = __float2bfloat16(x);
    return *reinterpret_cast<unsigned short*>(&h);
}

// split 16 consecutive floats into hi/lo bf16 pairs (x ~= hi + lo, err ~2^-16 rel)
__device__ __forceinline__ void split16(const float* __restrict__ p,
                                        ushort8& h0, ushort8& h1,
                                        ushort8& l0, ushort8& l1)
{
    #pragma unroll
    for (int q = 0; q < 2; q++) {
        float4 a = *(const float4*)(p + q * 8);
        float4 b = *(const float4*)(p + q * 8 + 4);
        float vv[8] = {a.x, a.y, a.z, a.w, b.x, b.y, b.z, b.w};
        #pragma unroll
        for (int j = 0; j < 8; j++) {
            unsigned short h = f2bf(vv[j]);
            float hf = __uint_as_float(((unsigned int)h) << 16);
            unsigned short l = f2bf(vv[j] - hf);
            if (q == 0) { h0[j] = h; l0[j] = l; }
            else        { h1[j] = h; l1[j] = l; }
        }
    }
}

// ---------------- K1: per-batch column mean of x ----------------
__global__ __launch_bounds__(256) void k1a(const float* __restrict__ x, float* __restrict__ partial) {
    int d = blockIdx.x * 256 + threadIdx.x;
    int b = blockIdx.y, c = blockIdx.z;
    const float* xp = x + ((size_t)b * TT + (size_t)c * CHL) * DD + d;
    float s = 0.0f;
    for (int t = 0; t < CHL; t++) s += xp[(size_t)t * DD];
    partial[(b * NCH + c) * DD + d] = s;
}

__global__ __launch_bounds__(256) void k1b(const float* __restrict__ partial, float* __restrict__ mean_x) {
    int d = blockIdx.x * 256 + threadIdx.x;
    int b = blockIdx.y;
    float s = 0.0f;
    for (int c = 0; c < NCH; c++) s += partial[(b * NCH + c) * DD + d];
    mean_x[b * DD + d] = s * (1.0f / TT);
}

// ---------------- K2: per-batch gctx + rq chain ----------------
__global__ __launch_bounds__(128) void k2_batch(
    const float* __restrict__ mean_x,
    const float* __restrict__ gpw, const float* __restrict__ gpb,
    const float* __restrict__ rq1w, const float* __restrict__ rq1b,
    const float* __restrict__ lnw, const float* __restrict__ lnb,
    const float* __restrict__ rq2w, const float* __restrict__ rq2b,
    float* __restrict__ gctx, float* __restrict__ rqv)
{
    int b = blockIdx.x, d = threadIdx.x;
    __shared__ __attribute__((aligned(16))) float g[DLb];
    __shared__ __attribute__((aligned(16))) float t1[DLb];
    __shared__ __attribute__((aligned(16))) float act[DLb];
    __shared__ float red[2];
    {
        const float4* wrow = (const float4*)(gpw + (size_t)d * DD);
        const float4* mx4  = (const float4*)(mean_x + (size_t)b * DD);
        float s = gpb[d];
        for (int k = 0; k < DD / 4; k++) {
            float4 w = wrow[k], m = mx4[k];
            s += w.x * m.x + w.y * m.y + w.z * m.z + w.w * m.w;
        }
        g[d] = s;
        gctx[b * DLb + d] = s;
    }
    __syncthreads();
    {
        float s = rq1b[d];
        for (int k = 0; k < DLb; k++) s += g[k] * rq1w[d * DLb + k];
        t1[d] = s;
    }
    __syncthreads();
    if (d == 0) {
        float m = 0.0f;
        for (int i = 0; i < DLb; i++) m += t1[i];
        m *= (1.0f / DLb);
        float v = 0.0f;
        for (int i = 0; i < DLb; i++) { float df = t1[i] - m; v += df * df; }
        v *= (1.0f / DLb);
        red[0] = m; red[1] = 1.0f / sqrtf(v + 1e-5f);
    }
    __syncthreads();
    {
        float xn = (t1[d] - red[0]) * red[1] * lnw[d] + lnb[d];
        act[d] = gelu_exact(xn);
    }
    __syncthreads();
    {
        float s = rq2b[d];
        for (int k = 0; k < DLb; k++) s += act[k] * rq2w[d * DLb + k];
        rqv[b * DLb + d] = s;
    }
}

// ---------------- K2b: fill seq position 0 with gctx ----------------
__global__ __launch_bounds__(256) void k2b(const float* __restrict__ gctx, float* __restrict__ seq) {
    int i = blockIdx.x * 256 + threadIdx.x;
    int n = i >> 7, d = i & 127;
    seq[(size_t)n * SEQSTR + d] = gctx[(n >> 11) * DLb + d];
}

#define RSA 40

// ---------------- K3s: seq[:,1:,:] = x @ w_down^T + pe  (split-bf16 MFMA) ----------------
__global__ __launch_bounds__(256) void k3s(const float* __restrict__ A,
                                           const float* __restrict__ W,
                                           const float* __restrict__ pe,
                                           float* __restrict__ seq)
{
    __shared__ __attribute__((aligned(16))) unsigned short Ah[128 * RSA];
    __shared__ __attribute__((aligned(16))) unsigned short Al[128 * RSA];
    __shared__ __attribute__((aligned(16))) unsigned short Bh[128 * RSA];
    __shared__ __attribute__((aligned(16))) unsigned short Bl[128 * RSA];
    int tid = threadIdx.x;
    int lane = tid & 63, wave = tid >> 6;
    int wm = wave & 1, wn = wave >> 1;
    int row0 = blockIdx.y * 128, col0 = blockIdx.x * 128;
    int fr = lane & 15, fq = lane >> 4;
    int sr = tid >> 1, sc = (tid & 1) * 16;
    f32x4 acc[4][4];
    #pragma unroll
    for (int i = 0; i < 4; i++)
        #pragma unroll
        for (int j = 0; j < 4; j++) acc[i][j] = (f32x4)0.0f;

    for (int k0 = 0; k0 < DD; k0 += 32) {
        ushort8 h0, h1, l0, l1;
        split16(&A[(size_t)(row0 + sr) * DD + k0 + sc], h0, h1, l0, l1);
        *(ushort8*)&Ah[sr * RSA + sc] = h0; *(ushort8*)&Ah[sr * RSA + sc + 8] = h1;
        *(ushort8*)&Al[sr * RSA + sc] = l0; *(ushort8*)&Al[sr * RSA + sc + 8] = l1;
        split16(&W[(size_t)(col0 + sr) * DD + k0 + sc], h0, h1, l0, l1);
        *(ushort8*)&Bh[sr * RSA + sc] = h0; *(ushort8*)&Bh[sr * RSA + sc + 8] = h1;
        *(ushort8*)&Bl[sr * RSA + sc] = l0; *(ushort8*)&Bl[sr * RSA + sc + 8] = l1;
        __syncthreads();
        short8 ah[4], al4[4], bh[4], bl4[4];
        #pragma unroll
        for (int f = 0; f < 4; f++) {
            int ra = (wm * 64 + f * 16 + fr) * RSA + fq * 8;
            int rb = (wn * 64 + f * 16 + fr) * RSA + fq * 8;
            ah[f]  = *(const short8*)&Ah[ra];
            al4[f] = *(const short8*)&Al[ra];
            bh[f]  = *(const short8*)&Bh[rb];
            bl4[f] = *(const short8*)&Bl[rb];
        }
        #pragma unroll
        for (int i = 0; i < 4; i++)
            #pragma unroll
            for (int j = 0; j < 4; j++) {
                acc[i][j] = __builtin_amdgcn_mfma_f32_16x16x32_bf16(ah[i],  bh[j],  acc[i][j], 0, 0, 0);
                acc[i][j] = __builtin_amdgcn_mfma_f32_16x16x32_bf16(ah[i],  bl4[j], acc[i][j], 0, 0, 0);
                acc[i][j] = __builtin_amdgcn_mfma_f32_16x16x32_bf16(al4[i], bh[j],  acc[i][j], 0, 0, 0);
            }
        __syncthreads();
    }
    #pragma unroll
    for (int j = 0; j < 4; j++) {
        int gc = col0 + wn * 64 + j * 16 + fr;
        float pv = pe[gc];
        #pragma unroll
        for (int i = 0; i < 4; i++) {
            #pragma unroll
            for (int r = 0; r < 4; r++) {
                int gr = row0 + wm * 64 + i * 16 + fq * 4 + r;
                seq[(size_t)gr * SEQSTR + DLb + gc] = acc[i][j][r] + pv;
            }
        }
    }
}

// ---------------- K4as: qkv slice GEMM (split-bf16 MFMA): C = A @ W^T + bias ----------------
// A: (TSL*9, 128) slice of seq; W: (384,128); C: (TSL*9, 384)
__global__ __launch_bounds__(256) void k4as(const float* __restrict__ A,
                                            const float* __restrict__ W,
                                            const float* __restrict__ bias,
                                            float* __restrict__ C)
{
    __shared__ __attribute__((aligned(16))) unsigned short Ah[128 * RSA];
    __shared__ __attribute__((aligned(16))) unsigned short Al[128 * RSA];
    __shared__ __attribute__((aligned(16))) unsigned short Bh[128 * RSA];
    __shared__ __attribute__((aligned(16))) unsigned short Bl[128 * RSA];
    int tid = threadIdx.x;
    int lane = tid & 63, wave = tid >> 6;
    int wm = wave & 1, wn = wave >> 1;
    int row0 = blockIdx.y * 128, col0 = blockIdx.x * 128;
    int fr = lane & 15, fq = lane >> 4;
    int sr = tid >> 1, sc = (tid & 1) * 16;
    f32x4 acc[4][4];
    #pragma unroll
    for (int i = 0; i < 4; i++)
        #pragma unroll
        for (int j = 0; j < 4; j++) acc[i][j] = (f32x4)0.0f;

    for (int k0 = 0; k0 < DLb; k0 += 32) {
        ushort8 h0, h1, l0, l1;
        split16(&A[(size_t)(row0 + sr) * DLb + k0 + sc], h0, h1, l0, l1);
        *(ushort8*)&Ah[sr * RSA + sc] = h0; *(ushort8*)&Ah[sr * RSA + sc + 8] = h1;
        *(ushort8*)&Al[sr * RSA + sc] = l0; *(ushort8*)&Al[sr * RSA + sc + 8] = l1;
        split16(&W[(size_t)(col0 + sr) * DLb + k0 + sc], h0, h1, l0, l1);
        *(ushort8*)&Bh[sr * RSA + sc] = h0; *(ushort8*)&Bh[sr * RSA + sc + 8] = h1;
        *(ushort8*)&Bl[sr * RSA + sc] = l0; *(ushort8*)&Bl[sr * RSA + sc + 8] = l1;
        __syncthreads();
        short8 ah[4], al4[4], bh[4], bl4[4];
        #pragma unroll
        for (int f = 0; f < 4; f++) {
            int ra = (wm * 64 + f * 16 + fr) * RSA + fq * 8;
            int rb = (wn * 64 + f * 16 + fr) * RSA + fq * 8;
            ah[f]  = *(const short8*)&Ah[ra];
            al4[f] = *(const short8*)&Al[ra];
            bh[f]  = *(const short8*)&Bh[rb];
            bl4[f] = *(const short8*)&Bl[rb];
        }
        #pragma unroll
        for (int i = 0; i < 4; i++)
            #pragma unroll
            for (int j = 0; j < 4; j++) {
                acc[i][j] = __builtin_amdgcn_mfma_f32_16x16x32_bf16(ah[i],  bh[j],  acc[i][j], 0, 0, 0);
                acc[i][j] = __builtin_amdgcn_mfma_f32_16x16x32_bf16(ah[i],  bl4[j], acc[i][j], 0, 0, 0);
                acc[i][j] = __builtin_amdgcn_mfma_f32_16x16x32_bf16(al4[i], bh[j],  acc[i][j], 0, 0, 0);
            }
        __syncthreads();
    }
    #pragma unroll
    for (int j = 0; j < 4; j++) {
        int gc = col0 + wn * 64 + j * 16 + fr;
        float bv = bias[gc];
        #pragma unroll
        for (int i = 0; i < 4; i++) {
            #pragma unroll
            for (int r = 0; r < 4; r++) {
                int gr = row0 + wm * 64 + i * 16 + fq * 4 + r;
                C[(size_t)gr * 384 + gc] = acc[i][j][r] + bv;
            }
        }
    }
}

// ---------------- K4b: per-token attention (softmax + attn@v), pos 1..8 only ----------------
__global__ __launch_bounds__(256) void k4b(const float* __restrict__ qkv,
                                           float* __restrict__ og, int n0)
{
    int nl = blockIdx.x;
    int tid = threadIdx.x;
    __shared__ __attribute__((aligned(16))) float sq[NPOS][384];
    __shared__ float attnw[HH][NPOS][12];
    {
        const float4* src = (const float4*)(qkv + (size_t)nl * NPOS * 384);
        float4* dst = (float4*)&sq[0][0];
        for (int i = tid; i < NPOS * 384 / 4; i += 256) dst[i] = src[i];
    }
    __syncthreads();
    if (tid < HH * NPOS) {
        int h = tid / NPOS, i = tid % NPOS;
        float sc[NPOS];
        float mx = -1e30f;
        for (int j = 0; j < NPOS; j++) {
            float s = 0.0f;
            for (int d2 = 0; d2 < HDh; d2++)
                s += sq[i][h * HDh + d2] * sq[j][DLb + h * HDh + d2];
            s *= 0.17677669529663687f;
            sc[j] = s;
            mx = fmaxf(mx, s);
        }
        float se = 0.0f;
        for (int j = 0; j < NPOS; j++) { sc[j] = expf(sc[j] - mx); se += sc[j]; }
        float inv = 1.0f / se;
        for (int j = 0; j < NPOS; j++) attnw[h][i][j] = sc[j] * inv;
    }
    __syncthreads();
    #pragma unroll
    for (int it = 0; it < 4; it++) {
        int idx = it * 256 + tid;
        int p = 1 + (idx >> 7), d = idx & 127, h = d >> 5;
        float s = 0.0f;
        #pragma unroll
        for (int j = 0; j < NPOS; j++) s += attnw[h][p][j] * sq[j][2 * DLb + d];
        og[((size_t)(n0 + nl) * 8 + (p - 1)) * DLb + d] = s;
    }
}

// ---------------- K4c: s2 = LN(o @ aow^T + aob + residual) ----------------
__global__ __launch_bounds__(256) void k4c(const float* __restrict__ A,
                                           const float* __restrict__ W,
                                           const float* __restrict__ bias,
                                           const float* __restrict__ seq,
                                           const float* __restrict__ nw,
                                           const float* __restrict__ nb,
                                           float* __restrict__ s2)
{
    __shared__ __attribute__((aligned(16))) float As[16][132];
    __shared__ __attribute__((aligned(16))) float Bs[16][132];
    __shared__ float redS[128][17];
    __shared__ float mstat[128][2];
    int tid = threadIdx.x;
    int tx = tid & 15, ty = tid >> 4;
    int row0 = blockIdx.y * 128;
    float acc[8][8] = {};
    for (int k0 = 0; k0 < DLb; k0 += 16) {
        #pragma unroll
        for (int i = 0; i < 2; i++) {
            int L = i * 256 + tid;
            int r = L >> 2, kq = (L & 3) * 4;
            float4 a4 = *(const float4*)&A[(size_t)(row0 + r) * DLb + k0 + kq];
            float4 b4 = *(const float4*)&W[(size_t)r * DLb + k0 + kq];
            As[kq + 0][r] = a4.x; As[kq + 1][r] = a4.y; As[kq + 2][r] = a4.z; As[kq + 3][r] = a4.w;
            Bs[kq + 0][r] = b4.x; Bs[kq + 1][r] = b4.y; Bs[kq + 2][r] = b4.z; Bs[kq + 3][r] = b4.w;
        }
        __syncthreads();
        #pragma unroll
        for (int kk = 0; kk < 16; kk++) {
            float4 a0 = *(const float4*)&As[kk][ty * 4];
            float4 a1 = *(const float4*)&As[kk][64 + ty * 4];
            float4 b0 = *(const float4*)&Bs[kk][tx * 4];
            float4 b1 = *(const float4*)&Bs[kk][64 + tx * 4];
            float ar[8] = {a0.x, a0.y, a0.z, a0.w, a1.x, a1.y, a1.z, a1.w};
            float bc[8] = {b0.x, b0.y, b0.z, b0.w, b1.x, b1.y, b1.z, b1.w};
            #pragma unroll
            for (int i = 0; i < 8; i++)
                #pragma unroll
                for (int j = 0; j < 8; j++)
                    acc[i][j] += ar[i] * bc[j];
        }
        __syncthreads();
    }
    float4 bb0 = *(const float4*)&bias[tx * 4];
    float4 bb1 = *(const float4*)&bias[64 + tx * 4];
    #pragma unroll
    for (int i = 0; i < 8; i++) {
        int rl = (i < 4) ? (ty * 4 + i) : (64 + ty * 4 + (i - 4));
        int m = row0 + rl;
        const float* res = seq + (size_t)(m >> 3) * SEQSTR + (size_t)((m & 7) + 1) * DLb;
        float4 r0 = *(const float4*)&res[tx * 4];
        float4 r1 = *(const float4*)&res[64 + tx * 4];
        acc[i][0] += bb0.x + r0.x; acc[i][1] += bb0.y + r0.y;
        acc[i][2] += bb0.z + r0.z; acc[i][3] += bb0.w + r0.w;
        acc[i][4] += bb1.x + r1.x; acc[i][5] += bb1.y + r1.y;
        acc[i][6] += bb1.z + r1.z; acc[i][7] += bb1.w + r1.w;
        float ps = 0.0f;
        #pragma unroll
        for (int j = 0; j < 8; j++) ps += acc[i][j];
        redS[rl][tx] = ps;
    }
    __syncthreads();
    if (tid < 128) {
        float s = 0.0f;
        #pragma unroll
        for (int t = 0; t < 16; t++) s += redS[tid][t];
        mstat[tid][0] = s * (1.0f / DLb);
    }
    __syncthreads();
    #pragma unroll
    for (int i = 0; i < 8; i++) {
        int rl = (i < 4) ? (ty * 4 + i) : (64 + ty * 4 + (i - 4));
        float m = mstat[rl][0];
        float pv = 0.0f;
        #pragma unroll
        for (int j = 0; j < 8; j++) { float df = acc[i][j] - m; pv += df * df; }
        redS[rl][tx] = pv;
    }
    __syncthreads();
    if (tid < 128) {
        float s = 0.0f;
        #pragma unroll
        for (int t = 0; t < 16; t++) s += redS[tid][t];
        mstat[tid][1] = 1.0f / sqrtf(s * (1.0f / DLb) + 1e-5f);
    }
    __syncthreads();
    float4 nw0 = *(const float4*)&nw[tx * 4];
    float4 nw1 = *(const float4*)&nw[64 + tx * 4];
    float4 nb0 = *(const float4*)&nb[tx * 4];
    float4 nb1 = *(const float4*)&nb[64 + tx * 4];
    #pragma unroll
    for (int i = 0; i < 8; i++) {
        int rl = (i < 4) ? (ty * 4 + i) : (64 + ty * 4 + (i - 4));
        float m = mstat[rl][0], istd = mstat[rl][1];
        float* dst = s2 + (size_t)(row0 + rl) * DLb;
        float4 o0, o1;
        o0.x = (acc[i][0] - m) * istd * nw0.x + nb0.x;
        o0.y = (acc[i][1] - m) * istd * nw0.y + nb0.y;
        o0.z = (acc[i][2] - m) * istd * nw0.z + nb0.z;
        o0.w = (acc[i][3] - m) * istd * nw0.w + nb0.w;
        o1.x = (acc[i][4] - m) * istd * nw1.x + nb1.x;
        o1.y = (acc[i][5] - m) * istd * nw1.y + nb1.y;
        o1.z = (acc[i][6] - m) * istd * nw1.z + nb1.z;
        o1.w = (acc[i][7] - m) * istd * nw1.w + nb1.w;
        *(float4*)&dst[tx * 4] = o0;
        *(float4*)&dst[64 + tx * 4] = o1;
    }
}

// ---------------- K4d: rk GEMM + fused logits ----------------
__global__ __launch_bounds__(256) void k4d(const float* __restrict__ A,
                                           const float* __restrict__ W,
                                           const float* __restrict__ bias,
                                           const float* __restrict__ rqv,
                                           float* __restrict__ logits)
{
    __shared__ __attribute__((aligned(16))) float As[16][132];
    __shared__ __attribute__((aligned(16))) float Bs[16][132];
    __shared__ float redS[128][17];
    int tid = threadIdx.x;
    int tx = tid & 15, ty = tid >> 4;
    int row0 = blockIdx.y * 128;
    float acc[8][8] = {};
    for (int k0 = 0; k0 < DLb; k0 += 16) {
        #pragma unroll
        for (int i = 0; i < 2; i++) {
            int L = i * 256 + tid;
            int r = L >> 2, kq = (L & 3) * 4;
            float4 a4 = *(const float4*)&A[(size_t)(row0 + r) * DLb + k0 + kq];
            float4 b4 = *(const float4*)&W[(size_t)r * DLb + k0 + kq];
            As[kq + 0][r] = a4.x; As[kq + 1][r] = a4.y; As[kq + 2][r] = a4.z; As[kq + 3][r] = a4.w;
            Bs[kq + 0][r] = b4.x; Bs[kq + 1][r] = b4.y; Bs[kq + 2][r] = b4.z; Bs[kq + 3][r] = b4.w;
        }
        __syncthreads();
        #pragma unroll
        for (int kk = 0; kk < 16; kk++) {
            float4 a0 = *(const float4*)&As[kk][ty * 4];
            float4 a1 = *(const float4*)&As[kk][64 + ty * 4];
            float4 b0 = *(const float4*)&Bs[kk][tx * 4];
            float4 b1 = *(const float4*)&Bs[kk][64 + tx * 4];
            float ar[8] = {a0.x, a0.y, a0.z, a0.w, a1.x, a1.y, a1.z, a1.w};
            float bc[8] = {b0.x, b0.y, b0.z, b0.w, b1.x, b1.y, b1.z, b1.w};
            #pragma unroll
            for (int i = 0; i < 8; i++)
                #pragma unroll
                for (int j = 0; j < 8; j++)
                    acc[i][j] += ar[i] * bc[j];
        }
        __syncthreads();
    }
    int b = row0 >> 14;
    const float* rq = rqv + b * DLb;
    float4 bb0 = *(const float4*)&bias[tx * 4];
    float4 bb1 = *(const float4*)&bias[64 + tx * 4];
    float4 q0 = *(const float4*)&rq[tx * 4];
    float4 q1 = *(const float4*)&rq[64 + tx * 4];
    #pragma unroll
    for (int i = 0; i < 8; i++) {
        int rl = (i < 4) ? (ty * 4 + i) : (64 + ty * 4 + (i - 4));
        float ps = (acc[i][0] + bb0.x) * q0.x + (acc[i][1] + bb0.y) * q0.y
                 + (acc[i][2] + bb0.z) * q0.z + (acc[i][3] + bb0.w) * q0.w
                 + (acc[i][4] + bb1.x) * q1.x + (acc[i][5] + bb1.y) * q1.y
                 + (acc[i][6] + bb1.z) * q1.z + (acc[i][7] + bb1.w) * q1.w;
        redS[rl][tx] = ps;
    }
    __syncthreads();
    if (tid < 128) {
        float s = 0.0f;
        #pragma unroll
        for (int t = 0; t < 16; t++) s += redS[tid][t];
        logits[row0 + tid] = s * 0.08838834764831845f;
    }
}

// ---------------- K4e: per-token softmax + top-3 + wsel ----------------
__global__ __launch_bounds__(256) void k4e(const float* __restrict__ logits,
                                           float* __restrict__ probs,
                                           float* __restrict__ wsel)
{
    int n = blockIdx.x * 256 + threadIdx.x;
    if (n >= NN) return;
    float lg[EE];
    float4 l0 = *(const float4*)&logits[(size_t)n * EE];
    float4 l1 = *(const float4*)&logits[(size_t)n * EE + 4];
    lg[0] = l0.x; lg[1] = l0.y; lg[2] = l0.z; lg[3] = l0.w;
    lg[4] = l1.x; lg[5] = l1.y; lg[6] = l1.z; lg[7] = l1.w;
    float mx = lg[0];
    #pragma unroll
    for (int e = 1; e < EE; e++) mx = fmaxf(mx, lg[e]);
    float pr[EE];
    float se = 0.0f;
    #pragma unroll
    for (int e = 0; e < EE; e++) { pr[e] = expf(lg[e] - mx); se += pr[e]; }
    float inv = 1.0f / se;
    #pragma unroll
    for (int e = 0; e < EE; e++) pr[e] *= inv;
    float4 p0, p1;
    p0.x = pr[0]; p0.y = pr[1]; p0.z = pr[2]; p0.w = pr[3];
    p1.x = pr[4]; p1.y = pr[5]; p1.z = pr[6]; p1.w = pr[7];
    *(float4*)&probs[(size_t)n * EE] = p0;
    *(float4*)&probs[(size_t)n * EE + 4] = p1;
    bool used[EE] = {};
    int sel[KK];
    float sw = 0.0f;
    for (int t = 0; t < KK; t++) {
        int bi = 0; float bv = -1e30f;
        for (int e = 0; e < EE; e++)
            if (!used[e] && pr[e] > bv) { bv = pr[e]; bi = e; }
        used[bi] = true; sel[t] = bi; sw += pr[bi];
    }
    float invsw = 1.0f / sw;
    float w8[EE];
    #pragma unroll
    for (int e = 0; e < EE; e++) w8[e] = 0.0f;
    for (int t = 0; t < KK; t++) w8[sel[t]] = pr[sel[t]] * invsw;
    float4 w0, w1;
    w0.x = w8[0]; w0.y = w8[1]; w0.z = w8[2]; w0.w = w8[3];
    w1.x = w8[4]; w1.y = w8[5]; w1.z = w8[6]; w1.w = w8[7];
    *(float4*)&wsel[(size_t)n * EE] = w0;
    *(float4*)&wsel[(size_t)n * EE + 4] = w1;
}

// ---------------- K5pre: a_bf16[n][k] = wsel[n][k>>7] * gelu(seq - pe) ----------------
__global__ __launch_bounds__(256) void k5pre(const float* __restrict__ seq,
                                             const float* __restrict__ pe,
                                             const float* __restrict__ wsel,
                                             unsigned short* __restrict__ abf)
{
    size_t g = ((size_t)blockIdx.x * 256 + threadIdx.x) * 8;
    int n = (int)(g >> 10), k0 = (int)(g & 1023);
    int e = k0 >> 7;
    float w = wsel[(size_t)n * EE + e];
    const float* sp = seq + (size_t)n * SEQSTR + DLb + k0;
    float4 s0 = *(const float4*)&sp[0];
    float4 s1 = *(const float4*)&sp[4];
    float4 p0 = *(const float4*)&pe[k0];
    float4 p1 = *(const float4*)&pe[k0 + 4];
    float v[8];
    v[0] = w * gelu_exact(s0.x - p0.x); v[1] = w * gelu_exact(s0.y - p0.y);
    v[2] = w * gelu_exact(s0.z - p0.z); v[3] = w * gelu_exact(s0.w - p0.w);
    v[4] = w * gelu_exact(s1.x - p1.x); v[5] = w * gelu_exact(s1.y - p1.y);
    v[6] = w * gelu_exact(s1.z - p1.z); v[7] = w * gelu_exact(s1.w - p1.w);
    ushort8 o;
    #pragma unroll
    for (int i = 0; i < 8; i++) o[i] = f2bf(v[i]);
    *(ushort8*)&abf[g] = o;
}

// ---------------- K5t: wupT[m][k] = bf16(wup[k][m]) ----------------
__global__ __launch_bounds__(256) void k5t(const float* __restrict__ wup, unsigned short* __restrict__ wupT) {
    __shared__ float T[64][68];
    int tid = threadIdx.x;
    int k0 = blockIdx.x * 64, m0 = blockIdx.y * 64;
    #pragma unroll
    for (int i = 0; i < 4; i++) {
        int F = i * 256 + tid;
        int r = F >> 4, c4 = (F & 15) * 4;
        *(float4*)&T[r][c4] = *(const float4*)&wup[(size_t)(k0 + r) * DD + m0 + c4];
    }
    __syncthreads();
    #pragma unroll
    for (int i = 0; i < 2; i++) {
        int W = i * 256 + tid;
        int r = W >> 3, c8 = (W & 7) * 8;
        ushort8 o;
        #pragma unroll
        for (int j = 0; j < 8; j++) o[j] = f2bf(T[c8 + j][r]);
        *(ushort8*)&wupT[(size_t)(m0 + r) * DD + k0 + c8] = o;
    }
}

// ---------------- K5: out = a_bf16 @ wupT^T via MFMA 16x16x32 bf16 ----------------
__global__ __launch_bounds__(256) void k5_mfma(const unsigned short* __restrict__ A,
                                               const unsigned short* __restrict__ B,
                                               float* __restrict__ C)
{
    __shared__ __attribute__((aligned(16))) unsigned short As[128 * RSA];
    __shared__ __attribute__((aligned(16))) unsigned short Bs[128 * RSA];
    int tid = threadIdx.x;
    int lane = tid & 63, wave = tid >> 6;
    int wm = wave & 1, wn = wave >> 1;
    int row0 = blockIdx.y * 128, col0 = blockIdx.x * 128;
    int fr = lane & 15, fq = lane >> 4;
    f32x4 acc[4][4];
    #pragma unroll
    for (int i = 0; i < 4; i++)
        #pragma unroll
        for (int j = 0; j < 4; j++) acc[i][j] = (f32x4)0.0f;

    for (int k0 = 0; k0 < DD; k0 += 32) {
        #pragma unroll
        for (int i = 0; i < 2; i++) {
            int L = i * 256 + tid;
            int r = L >> 2, q = (L & 3) * 8;
            *(ushort8*)&As[r * RSA + q] = *(const ushort8*)&A[(size_t)(row0 + r) * DD + k0 + q];
            *(ushort8*)&Bs[r * RSA + q] = *(const ushort8*)&B[(size_t)(col0 + r) * DD + k0 + q];
        }
        __syncthreads();
        short8 af[4], bf[4];
        #pragma unroll
        for (int f = 0; f < 4; f++) {
            af[f] = *(const short8*)&As[(wm * 64 + f * 16 + fr) * RSA + fq * 8];
            bf[f] = *(const short8*)&Bs[(wn * 64 + f * 16 + fr) * RSA + fq * 8];
        }
        #pragma unroll
        for (int i = 0; i < 4; i++)
            #pragma unroll
            for (int j = 0; j < 4; j++)
                acc[i][j] = __builtin_amdgcn_mfma_f32_16x16x32_bf16(af[i], bf[j], acc[i][j], 0, 0, 0);
        __syncthreads();
    }
    #pragma unroll
    for (int i = 0; i < 4; i++) {
        #pragma unroll
        for (int j = 0; j < 4; j++) {
            int gc = col0 + wn * 64 + j * 16 + fr;
            #pragma unroll
            for (int r = 0; r < 4; r++) {
                int gr = row0 + wm * 64 + i * 16 + fq * 4 + r;
                C[(size_t)gr * DD + gc] = acc[i][j][r];
            }
        }
    }
}

// ---------------- K6: aux loss ----------------
__global__ __launch_bounds__(256) void k6_aux(const float* __restrict__ probs,
                                              const float* __restrict__ wsel,
                                              float* __restrict__ out_aux)
{
    int tid = threadIdx.x;
    float lp[EE], lc[EE];
    #pragma unroll
    for (int e = 0; e < EE; e++) { lp[e] = 0.0f; lc[e] = 0.0f; }
    for (int n = tid; n < NN; n += 256) {
        #pragma unroll
        for (int e = 0; e < EE; e++) {
            lp[e] += probs[(size_t)n * EE + e];
            lc[e] += (wsel[(size_t)n * EE + e] > 0.0f) ? 1.0f : 0.0f;
        }
    }
    __shared__ float bp[256][EE];
    __shared__ float bc[256][EE];
    #pragma unroll
    for (int e = 0; e < EE; e++) { bp[tid][e] = lp[e]; bc[tid][e] = lc[e]; }
    __syncthreads();
    for (int s = 128; s > 0; s >>= 1) {
        if (tid < s) {
            #pragma unroll
            for (int e = 0; e < EE; e++) {
                bp[tid][e] += bp[tid + s][e];
                bc[tid][e] += bc[tid + s][e];
            }
        }
        __syncthreads();
    }
    if (tid == 0) {
        float a = 0.0f;
        for (int e = 0; e < EE; e++) a += (bp[0][e] / NN) * (bc[0][e] / NN);
        out_aux[0] = EE * a;
    }
}

extern "C" void kernel_launch(void* const* d_in, const int* in_sizes, int n_in,
                              void* d_out, int out_size, void* d_ws, size_t ws_size,
                              hipStream_t stream) {
    const float* x     = (const float*)d_in[0];
    const float* wdown = (const float*)d_in[1];
    const float* pe    = (const float*)d_in[2];
    const float* gpw   = (const float*)d_in[3];
    const float* gpb   = (const float*)d_in[4];
    const float* aiw   = (const float*)d_in[5];
    const float* aib   = (const float*)d_in[6];
    const float* aow   = (const float*)d_in[7];
    const float* aob   = (const float*)d_in[8];
    const float* nw    = (const float*)d_in[9];
    const float* nb    = (const float*)d_in[10];
    const float* rq1w  = (const float*)d_in[11];
    const float* rq1b  = (const float*)d_in[12];
    const float* rqlnw = (const float*)d_in[13];
    const float* rqlnb = (const float*)d_in[14];
    const float* rq2w  = (const float*)d_in[15];
    const float* rq2b  = (const float*)d_in[16];
    const float* rkw   = (const float*)d_in[17];
    const float* rkb   = (const float*)d_in[18];
    const float* wup   = (const float*)d_in[19];

    float* out = (float*)d_out;

    float* seq    = (float*)d_ws;                      // NN*1152
    float* o      = seq + (size_t)NN * SEQSTR;         // 65536*128
    float* region = o + (size_t)65536 * 128;           // qkv slices / s2
    float* qkvbuf = region;
    float* s2     = region;
    float* probs  = region + (size_t)65536 * 128;
    float* wsel   = probs + (size_t)NN * EE;
    float* logits = wsel + (size_t)NN * EE;
    float* partial= logits + (size_t)NN * EE;
    float* mean_x = partial + (size_t)BB * NCH * DD;
    float* gctx   = mean_x + (size_t)BB * DD;
    float* rqv    = gctx + (size_t)BB * DLb;
    unsigned short* wupT = (unsigned short*)(rqv + (size_t)BB * DLb);
    unsigned short* abf  = (unsigned short*)o;         // aliases o (dead after k4c)

    hipLaunchKernelGGL(k1a, dim3(DD / 256, BB, NCH), dim3(256), 0, stream, x, partial);
    hipLaunchKernelGGL(k1b, dim3(DD / 256, BB), dim3(256), 0, stream, partial, mean_x);
    hipLaunchKernelGGL(k2_batch, dim3(BB), dim3(DLb), 0, stream,
                       mean_x, gpw, gpb, rq1w, rq1b, rqlnw, rqlnb, rq2w, rq2b, gctx, rqv);
    hipLaunchKernelGGL(k2b, dim3(NN * DLb / 256), dim3(256), 0, stream, gctx, seq);
    hipLaunchKernelGGL(k3s, dim3((EE * DLb) / 128, NN / 128), dim3(256), 0, stream, x, wdown, pe, seq);
    for (int s = 0; s < NSLICE; s++) {
        hipLaunchKernelGGL(k4as, dim3(3, TSL * NPOS / 128), dim3(256), 0, stream,
                           seq + (size_t)s * TSL * SEQSTR, aiw, aib, qkvbuf);
        hipLaunchKernelGGL(k4b, dim3(TSL), dim3(256), 0, stream, qkvbuf, o, s * TSL);
    }
    hipLaunchKernelGGL(k4c, dim3(1, NN * EE / 128), dim3(256), 0, stream,
                       o, aow, aob, seq, nw, nb, s2);
    hipLaunchKernelGGL(k4d, dim3(1, NN * EE / 128), dim3(256), 0, stream,
                       s2, rkw, rkb, rqv, logits);
    hipLaunchKernelGGL(k4e, dim3(NN / 256), dim3(256), 0, stream, logits, probs, wsel);
    hipLaunchKernelGGL(k5t, dim3(DD / 64, DD / 64), dim3(256), 0, stream, wup, wupT);
    hipLaunchKernelGGL(k5pre, dim3(NN * DD / (256 * 8)), dim3(256), 0, stream, seq, pe, wsel, abf);
    hipLaunchKernelGGL(k5_mfma, dim3(DD / 128, NN / 128), dim3(256), 0, stream, abf, wupT, out);
    hipLaunchKernelGGL(k6_aux, dim3(1), dim3(256), 0, stream, probs, wsel, out + (size_t)NN * DD);
}